// Round 10
// baseline (786.286 us; speedup 1.0000x reference)
//
#include <hip/hip_runtime.h>
#include <hip/hip_bf16.h>
#include <math.h>

// Problem constants
#define NH    16
#define NOPE  128
#define ROPED 64
#define VD    128
#define QLR   1536
#define IH    8
#define ID    128
#define TOPK  8
#define EPSF  1e-5f
#define B_    2
#define S_    2048
#define H_    2048

using bf16 = __hip_bfloat16;
typedef __attribute__((ext_vector_type(8))) short short8;
typedef __attribute__((ext_vector_type(4))) short short4v;
typedef __attribute__((ext_vector_type(4))) float f32x4;

#define GLOBAL_AS __attribute__((address_space(1)))
#define LDS_AS    __attribute__((address_space(3)))

__device__ __forceinline__ float b2f(bf16 v) { return __bfloat162float(v); }
__device__ __forceinline__ bf16 f2b(float v) { return __float2bfloat16(v); }
__device__ __forceinline__ void stoC(float* p, float v) { *p = v; }
__device__ __forceinline__ void stoC(bf16* p, float v) { *p = __float2bfloat16(v); }

// ---------------------------------------------------------------------------
// Dedicated gate projection (exact fp32, verified R4).
// ---------------------------------------------------------------------------
__global__ __launch_bounds__(256) void gate_k(const float* __restrict__ x,
                                              const float* __restrict__ Wg,
                                              float* __restrict__ gate) {
    const int t = threadIdx.x;
    const int wid = t >> 6, lane = t & 63;
    const int row = blockIdx.x * 4 + wid;
    const float* xp = x + (size_t)row * H_;

    float acc[8] = {};
    for (int k0 = 0; k0 < H_; k0 += 256) {
        const int kb = k0 + lane * 4;
        const f32x4 xv = *(const f32x4*)(xp + kb);
        const f32x4 w0 = *(const f32x4*)(Wg + (size_t)kb * 8);
        const f32x4 w1 = *(const f32x4*)(Wg + (size_t)kb * 8 + 4);
        const f32x4 w2 = *(const f32x4*)(Wg + (size_t)(kb + 1) * 8);
        const f32x4 w3 = *(const f32x4*)(Wg + (size_t)(kb + 1) * 8 + 4);
        const f32x4 w4 = *(const f32x4*)(Wg + (size_t)(kb + 2) * 8);
        const f32x4 w5 = *(const f32x4*)(Wg + (size_t)(kb + 2) * 8 + 4);
        const f32x4 w6 = *(const f32x4*)(Wg + (size_t)(kb + 3) * 8);
        const f32x4 w7 = *(const f32x4*)(Wg + (size_t)(kb + 3) * 8 + 4);
#pragma unroll
        for (int j = 0; j < 4; j++) {
            acc[j]     += xv[0] * w0[j] + xv[1] * w2[j] + xv[2] * w4[j] + xv[3] * w6[j];
            acc[4 + j] += xv[0] * w1[j] + xv[1] * w3[j] + xv[2] * w5[j] + xv[3] * w7[j];
        }
    }
#pragma unroll
    for (int j = 0; j < 8; j++) {
#pragma unroll
        for (int off = 32; off > 0; off >>= 1)
            acc[j] += __shfl_xor(acc[j], off);
    }
    if (lane == 0) {
#pragma unroll
        for (int j = 0; j < 8; j++) gate[(size_t)row * 8 + j] = acc[j];
    }
}

// ---------------------------------------------------------------------------
// bf16 MFMA GEMM, m97 structure + bijective chunked XCD swizzle.
// ---------------------------------------------------------------------------
template <typename OT>
__global__ __launch_bounds__(256) void gemm_bt_mfma_k(const bf16* __restrict__ A,
                                                      const bf16* __restrict__ Bt,
                                                      OT* __restrict__ C,
                                                      int M, int N, int K) {
    __shared__ bf16 As[128 * 32];
    __shared__ bf16 Bs[128 * 32];
    const int t = threadIdx.x;
    const int w = t >> 6;
    const int l = t & 63;
    const int col = l & 15;
    const int quad = l >> 4;
    const int wm = w >> 1, wn = w & 1;

    const int gx = gridDim.x;
    const int nwg = gx * gridDim.y;
    const int lin = blockIdx.y * gx + blockIdx.x;
    const int work = (lin & 7) * (nwg >> 3) + (lin >> 3);
    const int row0 = (work / gx) * 128;
    const int col0 = (work % gx) * 128;

    const int rA = l >> 2;
    const int cA = (l & 3) * 8;
    const bf16* ga0 = A + (size_t)(row0 + w * 16 + rA) * K + cA;
    const bf16* ga1 = A + (size_t)(row0 + (4 + w) * 16 + rA) * K + cA;
    const bf16* gb0 = Bt + (size_t)(col0 + w * 16 + rA) * K + cA;
    const bf16* gb1 = Bt + (size_t)(col0 + (4 + w) * 16 + rA) * K + cA;
    bf16* lA0 = &As[w * 512];
    bf16* lA1 = &As[(4 + w) * 512];
    bf16* lB0 = &Bs[w * 512];
    bf16* lB1 = &Bs[(4 + w) * 512];

    f32x4 acc[4][4];
#pragma unroll
    for (int i = 0; i < 4; i++)
#pragma unroll
        for (int j = 0; j < 4; j++) acc[i][j] = (f32x4){0.f, 0.f, 0.f, 0.f};

    for (int k0 = 0; k0 < K; k0 += 32) {
        __syncthreads();
        __builtin_amdgcn_global_load_lds((const GLOBAL_AS void*)(ga0 + k0),
                                         (LDS_AS void*)lA0, 16, 0, 0);
        __builtin_amdgcn_global_load_lds((const GLOBAL_AS void*)(ga1 + k0),
                                         (LDS_AS void*)lA1, 16, 0, 0);
        __builtin_amdgcn_global_load_lds((const GLOBAL_AS void*)(gb0 + k0),
                                         (LDS_AS void*)lB0, 16, 0, 0);
        __builtin_amdgcn_global_load_lds((const GLOBAL_AS void*)(gb1 + k0),
                                         (LDS_AS void*)lB1, 16, 0, 0);
        __syncthreads();

        short8 af[4], bfr[4];
#pragma unroll
        for (int i = 0; i < 4; i++) {
            af[i]  = *(const short8*)&As[(wm * 64 + i * 16 + col) * 32 + quad * 8];
            bfr[i] = *(const short8*)&Bs[(wn * 64 + i * 16 + col) * 32 + quad * 8];
        }
#pragma unroll
        for (int i = 0; i < 4; i++)
#pragma unroll
            for (int j = 0; j < 4; j++)
                acc[i][j] = __builtin_amdgcn_mfma_f32_16x16x32_bf16(af[i], bfr[j], acc[i][j], 0, 0, 0);
    }

#pragma unroll
    for (int i = 0; i < 4; i++)
#pragma unroll
        for (int j = 0; j < 4; j++)
#pragma unroll
            for (int r = 0; r < 4; r++) {
                const int gr = row0 + wm * 64 + i * 16 + quad * 4 + r;
                const int gc = col0 + wn * 64 + j * 16 + col;
                stoC(C + (size_t)gr * N + gc, acc[i][j][r]);
            }
}

// ---------------------------------------------------------------------------
// Merged x-projection GEMM (cq | kvc only; ist ELIMINATED — sparse_k now
// computes only the 8 selected rows directly). N = 4608: rows [0,1536) =
// W_cq^T, [1536,4608) = W_ckv^T. Routing is block-uniform.
// ---------------------------------------------------------------------------
__global__ __launch_bounds__(256) void gemm_x2_k(const bf16* __restrict__ A,
                                                 const bf16* __restrict__ Bt,
                                                 float* __restrict__ cq,
                                                 bf16* __restrict__ kvc) {
    __shared__ bf16 As[128 * 32];
    __shared__ bf16 Bs[128 * 32];
    const int K = H_;
    const int t = threadIdx.x;
    const int w = t >> 6;
    const int l = t & 63;
    const int col = l & 15;
    const int quad = l >> 4;
    const int wm = w >> 1, wn = w & 1;

    const int gx = gridDim.x;
    const int nwg = gx * gridDim.y;
    const int lin = blockIdx.y * gx + blockIdx.x;
    const int work = (lin & 7) * (nwg >> 3) + (lin >> 3);
    const int row0 = (work / gx) * 128;
    const int col0 = (work % gx) * 128;

    const int rA = l >> 2;
    const int cA = (l & 3) * 8;
    const bf16* ga0 = A + (size_t)(row0 + w * 16 + rA) * K + cA;
    const bf16* ga1 = A + (size_t)(row0 + (4 + w) * 16 + rA) * K + cA;
    const bf16* gb0 = Bt + (size_t)(col0 + w * 16 + rA) * K + cA;
    const bf16* gb1 = Bt + (size_t)(col0 + (4 + w) * 16 + rA) * K + cA;
    bf16* lA0 = &As[w * 512];
    bf16* lA1 = &As[(4 + w) * 512];
    bf16* lB0 = &Bs[w * 512];
    bf16* lB1 = &Bs[(4 + w) * 512];

    f32x4 acc[4][4];
#pragma unroll
    for (int i = 0; i < 4; i++)
#pragma unroll
        for (int j = 0; j < 4; j++) acc[i][j] = (f32x4){0.f, 0.f, 0.f, 0.f};

    for (int k0 = 0; k0 < K; k0 += 32) {
        __syncthreads();
        __builtin_amdgcn_global_load_lds((const GLOBAL_AS void*)(ga0 + k0),
                                         (LDS_AS void*)lA0, 16, 0, 0);
        __builtin_amdgcn_global_load_lds((const GLOBAL_AS void*)(ga1 + k0),
                                         (LDS_AS void*)lA1, 16, 0, 0);
        __builtin_amdgcn_global_load_lds((const GLOBAL_AS void*)(gb0 + k0),
                                         (LDS_AS void*)lB0, 16, 0, 0);
        __builtin_amdgcn_global_load_lds((const GLOBAL_AS void*)(gb1 + k0),
                                         (LDS_AS void*)lB1, 16, 0, 0);
        __syncthreads();

        short8 af[4], bfr[4];
#pragma unroll
        for (int i = 0; i < 4; i++) {
            af[i]  = *(const short8*)&As[(wm * 64 + i * 16 + col) * 32 + quad * 8];
            bfr[i] = *(const short8*)&Bs[(wn * 64 + i * 16 + col) * 32 + quad * 8];
        }
#pragma unroll
        for (int i = 0; i < 4; i++)
#pragma unroll
            for (int j = 0; j < 4; j++)
                acc[i][j] = __builtin_amdgcn_mfma_f32_16x16x32_bf16(af[i], bfr[j], acc[i][j], 0, 0, 0);
    }

#pragma unroll
    for (int i = 0; i < 4; i++)
#pragma unroll
        for (int j = 0; j < 4; j++)
#pragma unroll
            for (int r = 0; r < 4; r++) {
                const int gr = row0 + wm * 64 + i * 16 + quad * 4 + r;
                const int gc = col0 + wn * 64 + j * 16 + col;
                const float v = acc[i][j][r];
                if (col0 < 1536) cq[(size_t)gr * QLR + gc] = v;
                else             kvc[(size_t)gr * 3072 + (gc - 1536)] = f2b(v);
            }
}

// ---------------------------------------------------------------------------
// W_q GEMM with FUSED RoPE epilogue. qp = cqb @ WqT, N=3072 = 16 heads
// x 192; cols with (g0%192)>=128 are rope pairs. Pair (2j,2j+1) sits in
// adjacent lanes (col parity == gc parity) -> one shfl_xor(1) per value.
// Replaces gemm_bt_mfma_k<bf16> + q_rope_k.
// ---------------------------------------------------------------------------
__global__ __launch_bounds__(256) void gemm_q_rope_k(const bf16* __restrict__ A,
                                                     const bf16* __restrict__ Bt,
                                                     bf16* __restrict__ qp) {
    __shared__ bf16 As[128 * 32];
    __shared__ bf16 Bs[128 * 32];
    const int K = QLR;
    const int N = 3072;
    const int t = threadIdx.x;
    const int w = t >> 6;
    const int l = t & 63;
    const int col = l & 15;
    const int quad = l >> 4;
    const int wm = w >> 1, wn = w & 1;

    const int gx = gridDim.x;
    const int nwg = gx * gridDim.y;
    const int lin = blockIdx.y * gx + blockIdx.x;
    const int work = (lin & 7) * (nwg >> 3) + (lin >> 3);
    const int row0 = (work / gx) * 128;
    const int col0 = (work % gx) * 128;

    const int rA = l >> 2;
    const int cA = (l & 3) * 8;
    const bf16* ga0 = A + (size_t)(row0 + w * 16 + rA) * K + cA;
    const bf16* ga1 = A + (size_t)(row0 + (4 + w) * 16 + rA) * K + cA;
    const bf16* gb0 = Bt + (size_t)(col0 + w * 16 + rA) * K + cA;
    const bf16* gb1 = Bt + (size_t)(col0 + (4 + w) * 16 + rA) * K + cA;
    bf16* lA0 = &As[w * 512];
    bf16* lA1 = &As[(4 + w) * 512];
    bf16* lB0 = &Bs[w * 512];
    bf16* lB1 = &Bs[(4 + w) * 512];

    f32x4 acc[4][4];
#pragma unroll
    for (int i = 0; i < 4; i++)
#pragma unroll
        for (int j = 0; j < 4; j++) acc[i][j] = (f32x4){0.f, 0.f, 0.f, 0.f};

    for (int k0 = 0; k0 < K; k0 += 32) {
        __syncthreads();
        __builtin_amdgcn_global_load_lds((const GLOBAL_AS void*)(ga0 + k0),
                                         (LDS_AS void*)lA0, 16, 0, 0);
        __builtin_amdgcn_global_load_lds((const GLOBAL_AS void*)(ga1 + k0),
                                         (LDS_AS void*)lA1, 16, 0, 0);
        __builtin_amdgcn_global_load_lds((const GLOBAL_AS void*)(gb0 + k0),
                                         (LDS_AS void*)lB0, 16, 0, 0);
        __builtin_amdgcn_global_load_lds((const GLOBAL_AS void*)(gb1 + k0),
                                         (LDS_AS void*)lB1, 16, 0, 0);
        __syncthreads();

        short8 af[4], bfr[4];
#pragma unroll
        for (int i = 0; i < 4; i++) {
            af[i]  = *(const short8*)&As[(wm * 64 + i * 16 + col) * 32 + quad * 8];
            bfr[i] = *(const short8*)&Bs[(wn * 64 + i * 16 + col) * 32 + quad * 8];
        }
#pragma unroll
        for (int i = 0; i < 4; i++)
#pragma unroll
            for (int j = 0; j < 4; j++)
                acc[i][j] = __builtin_amdgcn_mfma_f32_16x16x32_bf16(af[i], bfr[j], acc[i][j], 0, 0, 0);
    }

#pragma unroll
    for (int i = 0; i < 4; i++)
#pragma unroll
        for (int j = 0; j < 4; j++) {
            const int g0 = col0 + wn * 64 + j * 16;   // 16-col group base
            const int c0 = g0 % 192;                  // wave-uniform
            if (c0 >= 128) {
                // rope pair group: jj = (c0-128)/2 + col/2; parity = col&1
                const int jj = ((c0 - 128) >> 1) + (col >> 1);
                const float freq = exp2f(-0.41524101186092014f * (float)jj);
#pragma unroll
                for (int r = 0; r < 4; r++) {
                    const int gr = row0 + wm * 64 + i * 16 + quad * 4 + r;
                    const int s = gr & (S_ - 1);
                    const float own = acc[i][j][r];
                    const float other = __shfl_xor(own, 1);
                    float sn, cs; sincosf((float)s * freq, &sn, &cs);
                    const float v = (col & 1) ? (other * sn + own * cs)   // oi = xr*s + xi*c
                                              : (own * cs - other * sn);  // or = xr*c - xi*s
                    qp[(size_t)gr * N + g0 + col] = f2b(v);
                }
            } else {
#pragma unroll
                for (int r = 0; r < 4; r++) {
                    const int gr = row0 + wm * 64 + i * 16 + quad * 4 + r;
                    qp[(size_t)gr * N + g0 + col] = f2b(acc[i][j][r]);
                }
            }
        }
}

// ---------------------------------------------------------------------------
// kv matmul on MFMA (verified R5). col-block 0 -> kvc k_nope; col-block 1 ->
// VbT[bh][dv][s] packed 8B stores.
// ---------------------------------------------------------------------------
__global__ __launch_bounds__(256) void gemm_kv_k(const bf16* __restrict__ A,
                                                 const bf16* __restrict__ Bt,
                                                 bf16* __restrict__ kvc,
                                                 bf16* __restrict__ VbT) {
    __shared__ bf16 As[128 * 32];
    __shared__ bf16 Bs[128 * 32];
    const int K = 128;
    const int t = threadIdx.x;
    const int w = t >> 6;
    const int l = t & 63;
    const int col = l & 15;
    const int quad = l >> 4;
    const int wm = w >> 1, wn = w & 1;

    const int gx = gridDim.x;
    const int nwg = gx * gridDim.y;
    const int lin = blockIdx.y * gx + blockIdx.x;
    const int work = (lin & 7) * (nwg >> 3) + (lin >> 3);
    const int row0 = (work / gx) * 128;
    const int col0 = (work % gx) * 128;

    const int rA = l >> 2;
    const int cA = (l & 3) * 8;
    const bf16* ga0 = A + (size_t)(row0 + w * 16 + rA) * K + cA;
    const bf16* ga1 = A + (size_t)(row0 + (4 + w) * 16 + rA) * K + cA;
    const bf16* gb0 = Bt + (size_t)(col0 + w * 16 + rA) * K + cA;
    const bf16* gb1 = Bt + (size_t)(col0 + (4 + w) * 16 + rA) * K + cA;
    bf16* lA0 = &As[w * 512];
    bf16* lA1 = &As[(4 + w) * 512];
    bf16* lB0 = &Bs[w * 512];
    bf16* lB1 = &Bs[(4 + w) * 512];

    f32x4 acc[4][4];
#pragma unroll
    for (int i = 0; i < 4; i++)
#pragma unroll
        for (int j = 0; j < 4; j++) acc[i][j] = (f32x4){0.f, 0.f, 0.f, 0.f};

    for (int k0 = 0; k0 < K; k0 += 32) {
        __syncthreads();
        __builtin_amdgcn_global_load_lds((const GLOBAL_AS void*)(ga0 + k0),
                                         (LDS_AS void*)lA0, 16, 0, 0);
        __builtin_amdgcn_global_load_lds((const GLOBAL_AS void*)(ga1 + k0),
                                         (LDS_AS void*)lA1, 16, 0, 0);
        __builtin_amdgcn_global_load_lds((const GLOBAL_AS void*)(gb0 + k0),
                                         (LDS_AS void*)lB0, 16, 0, 0);
        __builtin_amdgcn_global_load_lds((const GLOBAL_AS void*)(gb1 + k0),
                                         (LDS_AS void*)lB1, 16, 0, 0);
        __syncthreads();

        short8 af[4], bfr[4];
#pragma unroll
        for (int i = 0; i < 4; i++) {
            af[i]  = *(const short8*)&As[(wm * 64 + i * 16 + col) * 32 + quad * 8];
            bfr[i] = *(const short8*)&Bs[(wn * 64 + i * 16 + col) * 32 + quad * 8];
        }
#pragma unroll
        for (int i = 0; i < 4; i++)
#pragma unroll
            for (int j = 0; j < 4; j++)
                acc[i][j] = __builtin_amdgcn_mfma_f32_16x16x32_bf16(af[i], bfr[j], acc[i][j], 0, 0, 0);
    }

    if (col0 == 0) {
#pragma unroll
        for (int i = 0; i < 4; i++)
#pragma unroll
            for (int j = 0; j < 4; j++)
#pragma unroll
                for (int r = 0; r < 4; r++) {
                    const int gr = row0 + wm * 64 + i * 16 + quad * 4 + r;
                    const int gc = wn * 64 + j * 16 + col;
                    kvc[(size_t)gr * 192 + gc] = f2b(acc[i][j][r]);
                }
    } else {
        const int bb = row0 >> 15;
        const int ssb = ((row0 >> 4) & (S_ - 1)) + wm * 4;
#pragma unroll
        for (int j = 0; j < 4; j++) {
            const int dv = wn * 64 + j * 16 + col;
#pragma unroll
            for (int r = 0; r < 4; r++) {
                const int hh = quad * 4 + r;
                short4v pk;
#pragma unroll
                for (int i = 0; i < 4; i++) {
                    bf16 v = f2b(acc[i][j][r]);
                    pk[i] = *(short*)&v;
                }
                *(short4v*)&VbT[((size_t)(bb * NH + hh) * 128 + dv) * S_ + ssb] = pk;
            }
        }
    }
}

// ---------------------------------------------------------------------------
// Wave-per-row LN of kv_nope -> bf16 kvn, plus RoPE of k_pe.
// ---------------------------------------------------------------------------
__global__ __launch_bounds__(256) void kv_ln_k(bf16* __restrict__ kvc,
                                               const float* __restrict__ knw,
                                               const float* __restrict__ knb,
                                               bf16* __restrict__ kvn) {
    const int idx = blockIdx.x * 4 + (threadIdx.x >> 6);   // row 0..65535
    const int lane = threadIdx.x & 63;
    const int s = (idx >> 4) & (S_ - 1);
    const size_t base = (size_t)idx * 192;

    const float v0 = b2f(kvc[base + 64 + lane]);
    const float v1 = b2f(kvc[base + 128 + lane]);
    float xr = 0.f, xi = 0.f;
    if (lane < 32) { xr = b2f(kvc[base + 2 * lane]); xi = b2f(kvc[base + 2 * lane + 1]); }

    float s1 = v0 + v1, s2 = v0 * v0 + v1 * v1;
#pragma unroll
    for (int off = 32; off > 0; off >>= 1) {
        s1 += __shfl_xor(s1, off);
        s2 += __shfl_xor(s2, off);
    }
    const float mu = s1 * (1.f / 128.f);
    const float rinv = rsqrtf(s2 * (1.f / 128.f) - mu * mu + EPSF);
    kvn[(size_t)idx * 128 + lane]      = f2b((v0 - mu) * rinv * knw[lane] + knb[lane]);
    kvn[(size_t)idx * 128 + lane + 64] = f2b((v1 - mu) * rinv * knw[lane + 64] + knb[lane + 64]);

    if (lane < 32) {
        const float freq = exp2f(-0.41524101186092014f * (float)lane); // 10000^(-2l/64)
        const float ang = (float)s * freq;
        float sn, c; sincosf(ang, &sn, &c);
        kvc[base + 128 + 2 * lane]     = f2b(xr * c - xi * sn);
        kvc[base + 128 + 2 * lane + 1] = f2b(xr * sn + xi * c);
    }
}

// ---------------------------------------------------------------------------
// Elementwise fp32 -> bf16 cast.
// ---------------------------------------------------------------------------
__global__ __launch_bounds__(256) void cast_bf16_k(const float* __restrict__ X,
                                                   bf16* __restrict__ Y, int n4) {
    for (int i = blockIdx.x * 256 + threadIdx.x; i < n4; i += gridDim.x * 256) {
        const f32x4 v = ((const f32x4*)X)[i];
        short4v o;
#pragma unroll
        for (int j = 0; j < 4; j++) {
            bf16 b = f2b(v[j]);
            o[j] = *(short*)&b;
        }
        ((short4v*)Y)[i] = o;
    }
}

// ---------------------------------------------------------------------------
// Tiled transpose-cast: W (KxN fp32) -> Wt (NxK bf16).
// ---------------------------------------------------------------------------
__global__ __launch_bounds__(256) void transpose_cast_k(const float* __restrict__ W,
                                                        bf16* __restrict__ Wt,
                                                        int K, int N) {
    __shared__ float tile[32][33];
    const int t = threadIdx.x;
    const int tx = t & 31, ty = t >> 5;
    const int n0 = blockIdx.x * 32;
    const int k0 = blockIdx.y * 32;
#pragma unroll
    for (int i = 0; i < 4; i++)
        tile[ty + 8 * i][tx] = W[(size_t)(k0 + ty + 8 * i) * N + n0 + tx];
    __syncthreads();
#pragma unroll
    for (int i = 0; i < 4; i++)
        Wt[(size_t)(n0 + ty + 8 * i) * K + k0 + tx] = f2b(tile[tx][ty + 8 * i]);
}

// ---------------------------------------------------------------------------
// Row layernorm emitting bf16.
// ---------------------------------------------------------------------------
__global__ __launch_bounds__(256) void layernorm_cast_k(const float* __restrict__ X,
                                                        const float* __restrict__ w,
                                                        const float* __restrict__ b,
                                                        bf16* __restrict__ Y,
                                                        int L) {
    __shared__ float r1[256], r2[256];
    const int row = blockIdx.x;
    const int t = threadIdx.x;
    const float* xp = X + (size_t)row * L;
    bf16* yp = Y + (size_t)row * L;
    float s1 = 0.f, s2 = 0.f;
    for (int j = t; j < L; j += 256) { const float v = xp[j]; s1 += v; s2 += v * v; }
    r1[t] = s1; r2[t] = s2; __syncthreads();
    for (int off = 128; off > 0; off >>= 1) {
        if (t < off) { r1[t] += r1[t + off]; r2[t] += r2[t + off]; }
        __syncthreads();
    }
    const float mu   = r1[0] / (float)L;
    const float var  = r2[0] / (float)L - mu * mu;
    const float rinv = rsqrtf(var + EPSF);
    for (int j = t; j < L; j += 256)
        yp[j] = f2b((xp[j] - mu) * rinv * w[j] + b[j]);
}

// ---------------------------------------------------------------------------
// Sparse branch v2: computes ONLY the TOPK selected ist rows directly from
// x @ W_ip[:, ih*ID:(ih+1)*ID] in exact fp32 (full ist GEMM eliminated).
// x row staged in g[] (free after top-k); float4 W reads; 8-chunk k-split
// reduced via sq[] scratch (overwritten by its real contents afterwards).
// ---------------------------------------------------------------------------
__global__ __launch_bounds__(256) void sparse_k(const float* __restrict__ gate,
                                                const float* __restrict__ x,
                                                const float* __restrict__ Wip,
                                                const float* __restrict__ Wsq,
                                                const float* __restrict__ Wsk,
                                                const float* __restrict__ Wsv,
                                                const float* __restrict__ Wio,
                                                float* __restrict__ io) {
    __shared__ float g[S_];
    __shared__ float sel[TOPK][ID];
    __shared__ float sq[TOPK][ID], sk[TOPK][ID], sv[TOPK][ID];
    __shared__ float sp[TOPK][TOPK];
    __shared__ float ms[ID];
    __shared__ float rv[256];
    __shared__ int ri[256];
    __shared__ int sidx[TOPK];
    const int bi = blockIdx.x;
    const int ih = bi % IH;
    const int b = bi / IH;
    const int t = threadIdx.x;

    for (int s = t; s < S_; s += 256) g[s] = gate[(size_t)(b * S_ + s) * IH + ih];
    __syncthreads();

    for (int r = 0; r < TOPK; r++) {
        float bv = -INFINITY; int bx = S_;
        for (int s = t; s < S_; s += 256) {
            const float v = g[s];
            if (v > bv) { bv = v; bx = s; }
        }
        rv[t] = bv; ri[t] = bx; __syncthreads();
        for (int off = 128; off > 0; off >>= 1) {
            if (t < off) {
                const float v2 = rv[t + off]; const int i2 = ri[t + off];
                if (v2 > rv[t] || (v2 == rv[t] && i2 < ri[t])) { rv[t] = v2; ri[t] = i2; }
            }
            __syncthreads();
        }
        if (t == 0) { sidx[r] = ri[0]; g[ri[0]] = -INFINITY; }
        __syncthreads();
    }

    // sel[r][n] = sum_k x[b, sidx[r], k] * Wip[k, ih*ID + n]  (fp32 exact)
    {
        float* sc = &sq[0][0];                 // 1024-float scratch
        const int n4 = (t & 31) * 4;           // n base 0..124
        const int kc = (t >> 5) * 256;         // k chunk base
        for (int r = 0; r < TOPK; r++) {
            const float* xrow = x + ((size_t)b * S_ + sidx[r]) * H_;
            __syncthreads();                   // previous iter's readers done
            for (int k = t; k < H_; k += 256) g[k] = xrow[k];
            __syncthreads();
            f32x4 a4 = (f32x4){0.f, 0.f, 0.f, 0.f};
            for (int k = 0; k < 256; k++) {
                const float xv = g[kc + k];
                const f32x4 wv = *(const f32x4*)&Wip[(size_t)(kc + k) * (IH * ID) + ih * ID + n4];
#pragma unroll
                for (int e = 0; e < 4; e++) a4[e] += xv * wv[e];
            }
            *(f32x4*)&sc[(t >> 5) * 128 + n4] = a4;
            __syncthreads();
            if (t < ID) {
                float a = 0.f;
#pragma unroll
                for (int c = 0; c < 8; c++) a += sc[c * 128 + t];
                sel[r][t] = a;
            }
        }
    }
    __syncthreads();

    for (int i = t; i < TOPK * ID; i += 256) {
        const int r = i >> 7, n = i & 127;
        float aq = 0.f, ak = 0.f, av = 0.f;
        for (int k = 0; k < 128; k++) {
            const float s = sel[r][k];
            aq += s * Wsq[k * ID + n];
            ak += s * Wsk[k * ID + n];
            av += s * Wsv[k * ID + n];
        }
        sq[r][n] = aq; sk[r][n] = ak; sv[r][n] = av;
    }
    __syncthreads();

    if (t < TOPK * TOPK) {
        const int r = t >> 3, c = t & 7;
        float a = 0.f;
        for (int k = 0; k < 128; k++) a += sq[r][k] * sk[c][k];
        sp[r][c] = a * 0.08838834764831845f;
    }
    __syncthreads();

    if (t < TOPK) {
        float m = -INFINITY;
        for (int c = 0; c < 8; c++) m = fmaxf(m, sp[t][c]);
        float e[8]; float sum = 0.f;
        for (int c = 0; c < 8; c++) { e[c] = expf(sp[t][c] - m); sum += e[c]; }
        for (int c = 0; c < 8; c++) sp[t][c] = e[c] / sum;
    }
    __syncthreads();

    if (t < ID) {
        float acc = 0.f;
        for (int r = 0; r < 8; r++) {
            float so = 0.f;
            for (int c = 0; c < 8; c++) so += sp[r][c] * sv[c][t];
            acc += so;
        }
        ms[t] = acc * 0.125f;
    }
    __syncthreads();

    if (t < ID) {
        float acc = 0.f;
        for (int k = 0; k < 128; k++) acc += ms[k] * Wio[(size_t)k * H_ + t];
        io[((size_t)b * IH + ih) * ID + t] = acc;
    }
}

// ---------------------------------------------------------------------------
// MFMA flash attention v6 (verified R8): one q-tile per block, heavy-first
// dispatch, pipeline staging, defer-max, (256,2) bounds.
// ---------------------------------------------------------------------------
__global__ __launch_bounds__(256, 2) void attn_mfma_k(const bf16* __restrict__ Qp,
                                                      const bf16* __restrict__ Kc,
                                                      const bf16* __restrict__ VbT,
                                                      const float* __restrict__ io,
                                                      bf16* __restrict__ O) {
    __shared__ unsigned short Kt[64 * 200];
    __shared__ unsigned short Vt[128 * 72];
    __shared__ unsigned short Ps[4 * 16 * 72];

    const int lin = blockIdx.x;
    const int qt = 31 - (lin >> 5);            // heavy-first
    const int hb = lin & 31;
    const int h = hb & 15;
    const int b = hb >> 4;
    const int q0 = qt * 64;

    const int t = threadIdx.x;
    const int lane = t & 63;
    const int wq = t >> 6;
    const int col = lane & 15;
    const int quad = lane >> 4;

    const float scale = 0.07216878364870322f;  // 1/sqrt(192)
    const bf16* vplane = VbT + (size_t)(b * NH + h) * 128 * (size_t)S_;

    const int kr = t >> 2;
    const int kc0 = (t & 3) * 48;
    const int vki0 = (t & 7) * 8;
    const int vdv = t >> 3;

    short8 qfrag[6];
    {
        const int q = q0 + wq * 16 + col;
        const short8* qrow = (const short8*)(Qp + ((size_t)(b * S_ + q) * NH + h) * 192);
#pragma unroll
        for (int kc = 0; kc < 6; kc++) qfrag[kc] = qrow[kc * 4 + quad];
    }

    float m_r[4], l_r[4];
#pragma unroll
    for (int r = 0; r < 4; r++) { m_r[r] = -1e30f; l_r[r] = 0.f; }
    f32x4 accO[8];
#pragma unroll
    for (int nt = 0; nt < 8; nt++) accO[nt] = (f32x4){0.f, 0.f, 0.f, 0.f};

    const int nkt = qt + 1;

    short8 kreg[6], vreg[4];
    {
        const short8* ksrc = (const short8*)(Kc + ((size_t)(b * S_ + kr) * NH + h) * 192 + kc0);
#pragma unroll
        for (int c = 0; c < 6; c++) kreg[c] = ksrc[c];
#pragma unroll
        for (int p = 0; p < 4; p++)
            vreg[p] = *(const short8*)(vplane + (size_t)(p * 32 + vdv) * S_ + vki0);
    }

    for (int kt = 0; kt < nkt; kt++) {
        const int kt0 = kt * 64;
        __syncthreads();
        {
            short8* dst = (short8*)&Kt[kr * 200 + kc0];
#pragma unroll
            for (int c = 0; c < 6; c++) dst[c] = kreg[c];
#pragma unroll
            for (int p = 0; p < 4; p++)
                *(short8*)&Vt[(p * 32 + vdv) * 72 + vki0] = vreg[p];
        }
        __syncthreads();

        if (kt + 1 < nkt) {
            const int nk0 = kt0 + 64;
            const short8* ksrc = (const short8*)(Kc + ((size_t)(b * S_ + nk0 + kr) * NH + h) * 192 + kc0);
#pragma unroll
            for (int c = 0; c < 6; c++) kreg[c] = ksrc[c];
#pragma unroll
            for (int p = 0; p < 4; p++)
                vreg[p] = *(const short8*)(vplane + (size_t)(p * 32 + vdv) * S_ + nk0 + vki0);
        }

        f32x4 s[4];
        __builtin_amdgcn_s_setprio(1);
#pragma unroll
        for (int nt = 0; nt < 4; nt++) {
            f32x4 acc = (f32x4){0.f, 0.f, 0.f, 0.f};
#pragma unroll
            for (int kc = 0; kc < 6; kc++) {
                const short8 kf = *(const short8*)&Kt[(nt * 16 + col) * 200 + kc * 32 + quad * 8];
                acc = __builtin_amdgcn_mfma_f32_16x16x32_bf16(qfrag[kc], kf, acc, 0, 0, 0);
            }
            s[nt] = acc;
        }
        __builtin_amdgcn_s_setprio(0);
#pragma unroll
        for (int nt = 0; nt < 4; nt++)
#pragma unroll
            for (int r = 0; r < 4; r++) {
                const int kg = kt0 + nt * 16 + col;
                const int qg = q0 + wq * 16 + quad * 4 + r;
                const float v = s[nt][r] * scale;
                s[nt][r] = (kg > qg) ? -1e30f : v;
            }
        float alpha[4];
#pragma unroll
        for (int r = 0; r < 4; r++) {
            float mt = fmaxf(fmaxf(s[0][r], s[1][r]), fmaxf(s[2][r], s[3][r]));
            mt = fmaxf(mt, __shfl_xor(mt, 1));
            mt = fmaxf(mt, __shfl_xor(mt, 2));
            mt = fmaxf(mt, __shfl_xor(mt, 4));
            mt = fmaxf(mt, __shfl_xor(mt, 8));
            const bool need = (mt > m_r[r] + 8.f);
            const float mn = need ? mt : m_r[r];
            alpha[r] = need ? __expf(m_r[r] - mn) : 1.f;
            m_r[r] = mn;
            float rs = 0.f;
#pragma unroll
            for (int nt = 0; nt < 4; nt++) {
                const float p = __expf(s[nt][r] - mn);
                s[nt][r] = p;
                rs += p;
            }
            rs += __shfl_xor(rs, 1);
            rs += __shfl_xor(rs, 2);
            rs += __shfl_xor(rs, 4);
            rs += __shfl_xor(rs, 8);
            l_r[r] = l_r[r] * alpha[r] + rs;
        }
        {
            unsigned short* pw = &Ps[wq * 1152];
#pragma unroll
            for (int nt = 0; nt < 4; nt++)
#pragma unroll
                for (int r = 0; r < 4; r++) {
                    bf16 hv = f2b(s[nt][r]);
                    pw[(quad * 4 + r) * 72 + nt * 16 + col] = *(unsigned short*)&hv;
                }
        }
        short8 pf[2];
#pragma unroll
        for (int kk = 0; kk < 2; kk++)
            pf[kk] = *(const short8*)&Ps[wq * 1152 + col * 72 + kk * 32 + quad * 8];
        if (!(alpha[0] == 1.f && alpha[1] == 1.f && alpha[2] == 1.f && alpha[3] == 1.f)) {
#pragma unroll
            for (int nt = 0; nt < 8; nt++)
#pragma unroll
                for (int r = 0; r < 4; r++) accO[nt][r] *= alpha[r];
        }
        __builtin_amdgcn_s_setprio(1);
#pragma unroll
        for (int nt = 0; nt < 8; nt++) {
#pragma unroll
            for (int kk = 0; kk < 2; kk++) {
                const short8 vf = *(const short8*)&Vt[(nt * 16 + col) * 72 + kk * 32 + quad * 8];
                accO[nt] = __builtin_amdgcn_mfma_f32_16x16x32_bf16(pf[kk], vf, accO[nt], 0, 0, 0);
            }
        }
        __builtin_amdgcn_s_setprio(0);
    }

    const float* iorow = io + ((size_t)b * IH + (h >> 1)) * ID;
    float rinv[4];
#pragma unroll
    for (int r = 0; r < 4; r++) rinv[r] = 1.f / l_r[r];
#pragma unroll
    for (int nt = 0; nt < 8; nt++) {
        const int dv = nt * 16 + col;
        const float iov = iorow[dv];
#pragma unroll
        for (int r = 0; r < 4; r++) {
            const int q = q0 + wq * 16 + quad * 4 + r;
            O[((size_t)(b * S_ + q) * NH + h) * VD + dv] = f2b(accO[nt][r] * rinv[r] + iov);
        }
    }
}

// ---------------------------------------------------------------------------
// Workspace timeline (all slots within proven ~100.8 MB):
//  S0 = ws+0       (33.5MB): WtM(18.9) -> cqb(12.6)+WqT(9.4 @+12.6M)
//                            -> kvn(16.8) -> attnb(16.8)+WoT(8.4 @+16.8M)
//  S1 = ws+32MB    (25.2MB): cq fp32 (25.2) -> qp bf16 (25.2)
//  S2 = ws+56MB    (25.2MB): kvc
//  S3 = ws+80MB    (16.8MB): VbT
//  S4 = ws+96MB    (131KB) : gate -> WkvT
//  S5 = ws+96MB+128KB      : iob
//  xb lives in d_out (dead after gemm_x2; out written last).
// ---------------------------------------------------------------------------
extern "C" void kernel_launch(void* const* d_in, const int* in_sizes, int n_in,
                              void* d_out, int out_size, void* d_ws, size_t ws_size,
                              hipStream_t stream) {
    const float* x      = (const float*)d_in[0];
    const float* W_cq   = (const float*)d_in[1];
    const float* qn_w   = (const float*)d_in[2];
    const float* qn_b   = (const float*)d_in[3];
    const float* W_q    = (const float*)d_in[4];
    const float* W_ckv  = (const float*)d_in[5];
    const float* kvn_w  = (const float*)d_in[6];
    const float* kvn_b  = (const float*)d_in[7];
    const float* W_kv   = (const float*)d_in[8];
    const float* W_o    = (const float*)d_in[9];
    const float* W_ip   = (const float*)d_in[10];
    const float* W_ig   = (const float*)d_in[11];
    const float* W_sq   = (const float*)d_in[12];
    const float* W_sk   = (const float*)d_in[13];
    const float* W_sv   = (const float*)d_in[14];
    const float* W_io   = (const float*)d_in[15];
    float* out = (float*)d_out;

    const int M = B_ * S_;

    char* wsb = (char*)d_ws;
    // S0 tenants
    bf16*  WtM   = (bf16*)wsb;                       // merged x-proj weights^T (18.9MB)
    bf16*  cqb   = (bf16*)wsb;                       // bf16 LN output (12.6MB)
    bf16*  WqT   = (bf16*)(wsb + 12582912);          // W_q^T (9.4MB)
    bf16*  kvn   = (bf16*)wsb;                       // LN'd kv_nope (16.8MB)
    bf16*  attnb = (bf16*)wsb;                       // attention out bf16 (16.8MB)
    bf16*  WoT   = (bf16*)(wsb + 16777216);          // W_o^T (8.4MB)
    // S1
    float* cq    = (float*)(wsb + 33554432);
    bf16*  qp    = (bf16*)(wsb + 33554432);
    // S2
    bf16*  kvc   = (bf16*)(wsb + 58720256);
    // S3
    bf16*  VbT   = (bf16*)(wsb + 83886080);
    // S4/S5
    float* gate  = (float*)(wsb + 100663296);
    bf16*  WkvT  = (bf16*)(wsb + 100663296);
    float* iob   = (float*)(wsb + 100794368);
    bf16*  xb    = (bf16*)d_out;

    dim3 blk(256);

    // 1. cast x -> bf16
    cast_bf16_k<<<dim3(2048), blk, 0, stream>>>(x, xb, M * H_ / 4);

    // 2. merged weight transposes: WtM rows [0,1536) = W_cq^T, [1536,4608) = W_ckv^T
    transpose_cast_k<<<dim3(QLR / 32, H_ / 32), blk, 0, stream>>>(W_cq, WtM, H_, QLR);
    transpose_cast_k<<<dim3(3072 / 32, H_ / 32), blk, 0, stream>>>(W_ckv, WtM + (size_t)1536 * H_, H_, 3072);

    // 3. merged GEMM: cq | kvc (ist eliminated)
    gemm_x2_k<<<dim3(4608 / 128, M / 128), blk, 0, stream>>>(xb, WtM, cq, kvc);

    // 4. LN -> cqb (frees WtM)
    layernorm_cast_k<<<dim3(M), blk, 0, stream>>>(cq, qn_w, qn_b, cqb, QLR);

    // 5-6. qp = cqb @ W_q with fused RoPE (cq dead -> qp in S1)
    transpose_cast_k<<<dim3(3072 / 32, QLR / 32), blk, 0, stream>>>(W_q, WqT, QLR, 3072);
    gemm_q_rope_k<<<dim3(3072 / 128, M / 128), blk, 0, stream>>>(cqb, WqT, qp);

    // 7. gate = x @ W_ig — EXACT fp32
    gate_k<<<dim3(M / 4), blk, 0, stream>>>(x, W_ig, gate);

    // 8. kv LN (cqb/WqT dead -> kvn in S0)
    kv_ln_k<<<dim3(B_ * S_ * NH / 4), blk, 0, stream>>>(kvc, kvn_w, kvn_b, kvn);

    // 9. sparse branch: top-k from gate, sel computed from x/W_ip in fp32
    sparse_k<<<dim3(B_ * IH), blk, 0, stream>>>(gate, x, W_ip, W_sq, W_sk, W_sv, W_io, iob);

    // 10-11. kv matmul (gate dead -> WkvT)
    transpose_cast_k<<<dim3(256 / 32, 128 / 32), blk, 0, stream>>>(W_kv, WkvT, 128, 256);
    gemm_kv_k<<<dim3(2, (B_ * S_ * NH) / 128), blk, 0, stream>>>(kvn, WkvT, kvc, VbT);

    // 12. attention, heavy-first single-tile grid (kvn dead -> attnb in S0)
    attn_mfma_k<<<dim3(1024), blk, 0, stream>>>(qp, kvc, VbT, iob, attnb);

    // 13-14. out = attnb @ W_o
    transpose_cast_k<<<dim3(H_ / 32, H_ / 32), blk, 0, stream>>>(W_o, WoT, H_, H_);
    gemm_bt_mfma_k<float><<<dim3(H_ / 128, M / 128), blk, 0, stream>>>(attnb, WoT, out, M, H_, H_);
}

// Round 11
// 757.116 us; speedup vs baseline: 1.0385x; 1.0385x over previous
//
#include <hip/hip_runtime.h>
#include <hip/hip_bf16.h>
#include <math.h>

// Problem constants
#define NH    16
#define NOPE  128
#define ROPED 64
#define VD    128
#define QLR   1536
#define IH    8
#define ID    128
#define TOPK  8
#define EPSF  1e-5f
#define B_    2
#define S_    2048
#define H_    2048

using bf16 = __hip_bfloat16;
typedef __attribute__((ext_vector_type(8))) short short8;
typedef __attribute__((ext_vector_type(4))) short short4v;
typedef __attribute__((ext_vector_type(4))) float f32x4;

#define GLOBAL_AS __attribute__((address_space(1)))
#define LDS_AS    __attribute__((address_space(3)))

__device__ __forceinline__ float b2f(bf16 v) { return __bfloat162float(v); }
__device__ __forceinline__ bf16 f2b(float v) { return __float2bfloat16(v); }
__device__ __forceinline__ void stoC(float* p, float v) { *p = v; }
__device__ __forceinline__ void stoC(bf16* p, float v) { *p = __float2bfloat16(v); }

// ---------------------------------------------------------------------------
// Dedicated gate projection (exact fp32, verified R4).
// ---------------------------------------------------------------------------
__global__ __launch_bounds__(256) void gate_k(const float* __restrict__ x,
                                              const float* __restrict__ Wg,
                                              float* __restrict__ gate) {
    const int t = threadIdx.x;
    const int wid = t >> 6, lane = t & 63;
    const int row = blockIdx.x * 4 + wid;
    const float* xp = x + (size_t)row * H_;

    float acc[8] = {};
    for (int k0 = 0; k0 < H_; k0 += 256) {
        const int kb = k0 + lane * 4;
        const f32x4 xv = *(const f32x4*)(xp + kb);
        const f32x4 w0 = *(const f32x4*)(Wg + (size_t)kb * 8);
        const f32x4 w1 = *(const f32x4*)(Wg + (size_t)kb * 8 + 4);
        const f32x4 w2 = *(const f32x4*)(Wg + (size_t)(kb + 1) * 8);
        const f32x4 w3 = *(const f32x4*)(Wg + (size_t)(kb + 1) * 8 + 4);
        const f32x4 w4 = *(const f32x4*)(Wg + (size_t)(kb + 2) * 8);
        const f32x4 w5 = *(const f32x4*)(Wg + (size_t)(kb + 2) * 8 + 4);
        const f32x4 w6 = *(const f32x4*)(Wg + (size_t)(kb + 3) * 8);
        const f32x4 w7 = *(const f32x4*)(Wg + (size_t)(kb + 3) * 8 + 4);
#pragma unroll
        for (int j = 0; j < 4; j++) {
            acc[j]     += xv[0] * w0[j] + xv[1] * w2[j] + xv[2] * w4[j] + xv[3] * w6[j];
            acc[4 + j] += xv[0] * w1[j] + xv[1] * w3[j] + xv[2] * w5[j] + xv[3] * w7[j];
        }
    }
#pragma unroll
    for (int j = 0; j < 8; j++) {
#pragma unroll
        for (int off = 32; off > 0; off >>= 1)
            acc[j] += __shfl_xor(acc[j], off);
    }
    if (lane == 0) {
#pragma unroll
        for (int j = 0; j < 8; j++) gate[(size_t)row * 8 + j] = acc[j];
    }
}

// ---------------------------------------------------------------------------
// bf16 MFMA GEMM, m97 structure + bijective chunked XCD swizzle.
// ---------------------------------------------------------------------------
template <typename OT>
__global__ __launch_bounds__(256) void gemm_bt_mfma_k(const bf16* __restrict__ A,
                                                      const bf16* __restrict__ Bt,
                                                      OT* __restrict__ C,
                                                      int M, int N, int K) {
    __shared__ bf16 As[128 * 32];
    __shared__ bf16 Bs[128 * 32];
    const int t = threadIdx.x;
    const int w = t >> 6;
    const int l = t & 63;
    const int col = l & 15;
    const int quad = l >> 4;
    const int wm = w >> 1, wn = w & 1;

    const int gx = gridDim.x;
    const int nwg = gx * gridDim.y;
    const int lin = blockIdx.y * gx + blockIdx.x;
    const int work = (lin & 7) * (nwg >> 3) + (lin >> 3);
    const int row0 = (work / gx) * 128;
    const int col0 = (work % gx) * 128;

    const int rA = l >> 2;
    const int cA = (l & 3) * 8;
    const bf16* ga0 = A + (size_t)(row0 + w * 16 + rA) * K + cA;
    const bf16* ga1 = A + (size_t)(row0 + (4 + w) * 16 + rA) * K + cA;
    const bf16* gb0 = Bt + (size_t)(col0 + w * 16 + rA) * K + cA;
    const bf16* gb1 = Bt + (size_t)(col0 + (4 + w) * 16 + rA) * K + cA;
    bf16* lA0 = &As[w * 512];
    bf16* lA1 = &As[(4 + w) * 512];
    bf16* lB0 = &Bs[w * 512];
    bf16* lB1 = &Bs[(4 + w) * 512];

    f32x4 acc[4][4];
#pragma unroll
    for (int i = 0; i < 4; i++)
#pragma unroll
        for (int j = 0; j < 4; j++) acc[i][j] = (f32x4){0.f, 0.f, 0.f, 0.f};

    for (int k0 = 0; k0 < K; k0 += 32) {
        __syncthreads();
        __builtin_amdgcn_global_load_lds((const GLOBAL_AS void*)(ga0 + k0),
                                         (LDS_AS void*)lA0, 16, 0, 0);
        __builtin_amdgcn_global_load_lds((const GLOBAL_AS void*)(ga1 + k0),
                                         (LDS_AS void*)lA1, 16, 0, 0);
        __builtin_amdgcn_global_load_lds((const GLOBAL_AS void*)(gb0 + k0),
                                         (LDS_AS void*)lB0, 16, 0, 0);
        __builtin_amdgcn_global_load_lds((const GLOBAL_AS void*)(gb1 + k0),
                                         (LDS_AS void*)lB1, 16, 0, 0);
        __syncthreads();

        short8 af[4], bfr[4];
#pragma unroll
        for (int i = 0; i < 4; i++) {
            af[i]  = *(const short8*)&As[(wm * 64 + i * 16 + col) * 32 + quad * 8];
            bfr[i] = *(const short8*)&Bs[(wn * 64 + i * 16 + col) * 32 + quad * 8];
        }
#pragma unroll
        for (int i = 0; i < 4; i++)
#pragma unroll
            for (int j = 0; j < 4; j++)
                acc[i][j] = __builtin_amdgcn_mfma_f32_16x16x32_bf16(af[i], bfr[j], acc[i][j], 0, 0, 0);
    }

#pragma unroll
    for (int i = 0; i < 4; i++)
#pragma unroll
        for (int j = 0; j < 4; j++)
#pragma unroll
            for (int r = 0; r < 4; r++) {
                const int gr = row0 + wm * 64 + i * 16 + quad * 4 + r;
                const int gc = col0 + wn * 64 + j * 16 + col;
                stoC(C + (size_t)gr * N + gc, acc[i][j][r]);
            }
}

// ---------------------------------------------------------------------------
// Merged x-projection GEMM (cq | kvc only; ist eliminated). N = 4608:
// rows [0,1536) = W_cq^T, [1536,4608) = W_ckv^T. Routing block-uniform.
// ---------------------------------------------------------------------------
__global__ __launch_bounds__(256) void gemm_x2_k(const bf16* __restrict__ A,
                                                 const bf16* __restrict__ Bt,
                                                 float* __restrict__ cq,
                                                 bf16* __restrict__ kvc) {
    __shared__ bf16 As[128 * 32];
    __shared__ bf16 Bs[128 * 32];
    const int K = H_;
    const int t = threadIdx.x;
    const int w = t >> 6;
    const int l = t & 63;
    const int col = l & 15;
    const int quad = l >> 4;
    const int wm = w >> 1, wn = w & 1;

    const int gx = gridDim.x;
    const int nwg = gx * gridDim.y;
    const int lin = blockIdx.y * gx + blockIdx.x;
    const int work = (lin & 7) * (nwg >> 3) + (lin >> 3);
    const int row0 = (work / gx) * 128;
    const int col0 = (work % gx) * 128;

    const int rA = l >> 2;
    const int cA = (l & 3) * 8;
    const bf16* ga0 = A + (size_t)(row0 + w * 16 + rA) * K + cA;
    const bf16* ga1 = A + (size_t)(row0 + (4 + w) * 16 + rA) * K + cA;
    const bf16* gb0 = Bt + (size_t)(col0 + w * 16 + rA) * K + cA;
    const bf16* gb1 = Bt + (size_t)(col0 + (4 + w) * 16 + rA) * K + cA;
    bf16* lA0 = &As[w * 512];
    bf16* lA1 = &As[(4 + w) * 512];
    bf16* lB0 = &Bs[w * 512];
    bf16* lB1 = &Bs[(4 + w) * 512];

    f32x4 acc[4][4];
#pragma unroll
    for (int i = 0; i < 4; i++)
#pragma unroll
        for (int j = 0; j < 4; j++) acc[i][j] = (f32x4){0.f, 0.f, 0.f, 0.f};

    for (int k0 = 0; k0 < K; k0 += 32) {
        __syncthreads();
        __builtin_amdgcn_global_load_lds((const GLOBAL_AS void*)(ga0 + k0),
                                         (LDS_AS void*)lA0, 16, 0, 0);
        __builtin_amdgcn_global_load_lds((const GLOBAL_AS void*)(ga1 + k0),
                                         (LDS_AS void*)lA1, 16, 0, 0);
        __builtin_amdgcn_global_load_lds((const GLOBAL_AS void*)(gb0 + k0),
                                         (LDS_AS void*)lB0, 16, 0, 0);
        __builtin_amdgcn_global_load_lds((const GLOBAL_AS void*)(gb1 + k0),
                                         (LDS_AS void*)lB1, 16, 0, 0);
        __syncthreads();

        short8 af[4], bfr[4];
#pragma unroll
        for (int i = 0; i < 4; i++) {
            af[i]  = *(const short8*)&As[(wm * 64 + i * 16 + col) * 32 + quad * 8];
            bfr[i] = *(const short8*)&Bs[(wn * 64 + i * 16 + col) * 32 + quad * 8];
        }
#pragma unroll
        for (int i = 0; i < 4; i++)
#pragma unroll
            for (int j = 0; j < 4; j++)
                acc[i][j] = __builtin_amdgcn_mfma_f32_16x16x32_bf16(af[i], bfr[j], acc[i][j], 0, 0, 0);
    }

#pragma unroll
    for (int i = 0; i < 4; i++)
#pragma unroll
        for (int j = 0; j < 4; j++)
#pragma unroll
            for (int r = 0; r < 4; r++) {
                const int gr = row0 + wm * 64 + i * 16 + quad * 4 + r;
                const int gc = col0 + wn * 64 + j * 16 + col;
                const float v = acc[i][j][r];
                if (col0 < 1536) cq[(size_t)gr * QLR + gc] = v;
                else             kvc[(size_t)gr * 3072 + (gc - 1536)] = f2b(v);
            }
}

// ---------------------------------------------------------------------------
// W_q GEMM with FUSED RoPE epilogue (verified structure R10).
// ---------------------------------------------------------------------------
__global__ __launch_bounds__(256) void gemm_q_rope_k(const bf16* __restrict__ A,
                                                     const bf16* __restrict__ Bt,
                                                     bf16* __restrict__ qp) {
    __shared__ bf16 As[128 * 32];
    __shared__ bf16 Bs[128 * 32];
    const int K = QLR;
    const int N = 3072;
    const int t = threadIdx.x;
    const int w = t >> 6;
    const int l = t & 63;
    const int col = l & 15;
    const int quad = l >> 4;
    const int wm = w >> 1, wn = w & 1;

    const int gx = gridDim.x;
    const int nwg = gx * gridDim.y;
    const int lin = blockIdx.y * gx + blockIdx.x;
    const int work = (lin & 7) * (nwg >> 3) + (lin >> 3);
    const int row0 = (work / gx) * 128;
    const int col0 = (work % gx) * 128;

    const int rA = l >> 2;
    const int cA = (l & 3) * 8;
    const bf16* ga0 = A + (size_t)(row0 + w * 16 + rA) * K + cA;
    const bf16* ga1 = A + (size_t)(row0 + (4 + w) * 16 + rA) * K + cA;
    const bf16* gb0 = Bt + (size_t)(col0 + w * 16 + rA) * K + cA;
    const bf16* gb1 = Bt + (size_t)(col0 + (4 + w) * 16 + rA) * K + cA;
    bf16* lA0 = &As[w * 512];
    bf16* lA1 = &As[(4 + w) * 512];
    bf16* lB0 = &Bs[w * 512];
    bf16* lB1 = &Bs[(4 + w) * 512];

    f32x4 acc[4][4];
#pragma unroll
    for (int i = 0; i < 4; i++)
#pragma unroll
        for (int j = 0; j < 4; j++) acc[i][j] = (f32x4){0.f, 0.f, 0.f, 0.f};

    for (int k0 = 0; k0 < K; k0 += 32) {
        __syncthreads();
        __builtin_amdgcn_global_load_lds((const GLOBAL_AS void*)(ga0 + k0),
                                         (LDS_AS void*)lA0, 16, 0, 0);
        __builtin_amdgcn_global_load_lds((const GLOBAL_AS void*)(ga1 + k0),
                                         (LDS_AS void*)lA1, 16, 0, 0);
        __builtin_amdgcn_global_load_lds((const GLOBAL_AS void*)(gb0 + k0),
                                         (LDS_AS void*)lB0, 16, 0, 0);
        __builtin_amdgcn_global_load_lds((const GLOBAL_AS void*)(gb1 + k0),
                                         (LDS_AS void*)lB1, 16, 0, 0);
        __syncthreads();

        short8 af[4], bfr[4];
#pragma unroll
        for (int i = 0; i < 4; i++) {
            af[i]  = *(const short8*)&As[(wm * 64 + i * 16 + col) * 32 + quad * 8];
            bfr[i] = *(const short8*)&Bs[(wn * 64 + i * 16 + col) * 32 + quad * 8];
        }
#pragma unroll
        for (int i = 0; i < 4; i++)
#pragma unroll
            for (int j = 0; j < 4; j++)
                acc[i][j] = __builtin_amdgcn_mfma_f32_16x16x32_bf16(af[i], bfr[j], acc[i][j], 0, 0, 0);
    }

#pragma unroll
    for (int i = 0; i < 4; i++)
#pragma unroll
        for (int j = 0; j < 4; j++) {
            const int g0 = col0 + wn * 64 + j * 16;   // 16-col group base
            const int c0 = g0 % 192;                  // wave-uniform
            if (c0 >= 128) {
                const int jj = ((c0 - 128) >> 1) + (col >> 1);
                const float freq = exp2f(-0.41524101186092014f * (float)jj);
#pragma unroll
                for (int r = 0; r < 4; r++) {
                    const int gr = row0 + wm * 64 + i * 16 + quad * 4 + r;
                    const int s = gr & (S_ - 1);
                    const float own = acc[i][j][r];
                    const float other = __shfl_xor(own, 1);
                    float sn, cs; sincosf((float)s * freq, &sn, &cs);
                    const float v = (col & 1) ? (other * sn + own * cs)
                                              : (own * cs - other * sn);
                    qp[(size_t)gr * N + g0 + col] = f2b(v);
                }
            } else {
#pragma unroll
                for (int r = 0; r < 4; r++) {
                    const int gr = row0 + wm * 64 + i * 16 + quad * 4 + r;
                    qp[(size_t)gr * N + g0 + col] = f2b(acc[i][j][r]);
                }
            }
        }
}

// ---------------------------------------------------------------------------
// kv matmul on MFMA (verified R5). col-block 0 -> kvc k_nope; col-block 1 ->
// VbT[bh][dv][s] packed 8B stores.
// ---------------------------------------------------------------------------
__global__ __launch_bounds__(256) void gemm_kv_k(const bf16* __restrict__ A,
                                                 const bf16* __restrict__ Bt,
                                                 bf16* __restrict__ kvc,
                                                 bf16* __restrict__ VbT) {
    __shared__ bf16 As[128 * 32];
    __shared__ bf16 Bs[128 * 32];
    const int K = 128;
    const int t = threadIdx.x;
    const int w = t >> 6;
    const int l = t & 63;
    const int col = l & 15;
    const int quad = l >> 4;
    const int wm = w >> 1, wn = w & 1;

    const int gx = gridDim.x;
    const int nwg = gx * gridDim.y;
    const int lin = blockIdx.y * gx + blockIdx.x;
    const int work = (lin & 7) * (nwg >> 3) + (lin >> 3);
    const int row0 = (work / gx) * 128;
    const int col0 = (work % gx) * 128;

    const int rA = l >> 2;
    const int cA = (l & 3) * 8;
    const bf16* ga0 = A + (size_t)(row0 + w * 16 + rA) * K + cA;
    const bf16* ga1 = A + (size_t)(row0 + (4 + w) * 16 + rA) * K + cA;
    const bf16* gb0 = Bt + (size_t)(col0 + w * 16 + rA) * K + cA;
    const bf16* gb1 = Bt + (size_t)(col0 + (4 + w) * 16 + rA) * K + cA;
    bf16* lA0 = &As[w * 512];
    bf16* lA1 = &As[(4 + w) * 512];
    bf16* lB0 = &Bs[w * 512];
    bf16* lB1 = &Bs[(4 + w) * 512];

    f32x4 acc[4][4];
#pragma unroll
    for (int i = 0; i < 4; i++)
#pragma unroll
        for (int j = 0; j < 4; j++) acc[i][j] = (f32x4){0.f, 0.f, 0.f, 0.f};

    for (int k0 = 0; k0 < K; k0 += 32) {
        __syncthreads();
        __builtin_amdgcn_global_load_lds((const GLOBAL_AS void*)(ga0 + k0),
                                         (LDS_AS void*)lA0, 16, 0, 0);
        __builtin_amdgcn_global_load_lds((const GLOBAL_AS void*)(ga1 + k0),
                                         (LDS_AS void*)lA1, 16, 0, 0);
        __builtin_amdgcn_global_load_lds((const GLOBAL_AS void*)(gb0 + k0),
                                         (LDS_AS void*)lB0, 16, 0, 0);
        __builtin_amdgcn_global_load_lds((const GLOBAL_AS void*)(gb1 + k0),
                                         (LDS_AS void*)lB1, 16, 0, 0);
        __syncthreads();

        short8 af[4], bfr[4];
#pragma unroll
        for (int i = 0; i < 4; i++) {
            af[i]  = *(const short8*)&As[(wm * 64 + i * 16 + col) * 32 + quad * 8];
            bfr[i] = *(const short8*)&Bs[(wn * 64 + i * 16 + col) * 32 + quad * 8];
        }
#pragma unroll
        for (int i = 0; i < 4; i++)
#pragma unroll
            for (int j = 0; j < 4; j++)
                acc[i][j] = __builtin_amdgcn_mfma_f32_16x16x32_bf16(af[i], bfr[j], acc[i][j], 0, 0, 0);
    }

    if (col0 == 0) {
#pragma unroll
        for (int i = 0; i < 4; i++)
#pragma unroll
            for (int j = 0; j < 4; j++)
#pragma unroll
                for (int r = 0; r < 4; r++) {
                    const int gr = row0 + wm * 64 + i * 16 + quad * 4 + r;
                    const int gc = wn * 64 + j * 16 + col;
                    kvc[(size_t)gr * 192 + gc] = f2b(acc[i][j][r]);
                }
    } else {
        const int bb = row0 >> 15;
        const int ssb = ((row0 >> 4) & (S_ - 1)) + wm * 4;
#pragma unroll
        for (int j = 0; j < 4; j++) {
            const int dv = wn * 64 + j * 16 + col;
#pragma unroll
            for (int r = 0; r < 4; r++) {
                const int hh = quad * 4 + r;
                short4v pk;
#pragma unroll
                for (int i = 0; i < 4; i++) {
                    bf16 v = f2b(acc[i][j][r]);
                    pk[i] = *(short*)&v;
                }
                *(short4v*)&VbT[((size_t)(bb * NH + hh) * 128 + dv) * S_ + ssb] = pk;
            }
        }
    }
}

// ---------------------------------------------------------------------------
// Wave-per-row LN of kv_nope -> bf16 kvn, plus RoPE of k_pe.
// ---------------------------------------------------------------------------
__global__ __launch_bounds__(256) void kv_ln_k(bf16* __restrict__ kvc,
                                               const float* __restrict__ knw,
                                               const float* __restrict__ knb,
                                               bf16* __restrict__ kvn) {
    const int idx = blockIdx.x * 4 + (threadIdx.x >> 6);   // row 0..65535
    const int lane = threadIdx.x & 63;
    const int s = (idx >> 4) & (S_ - 1);
    const size_t base = (size_t)idx * 192;

    const float v0 = b2f(kvc[base + 64 + lane]);
    const float v1 = b2f(kvc[base + 128 + lane]);
    float xr = 0.f, xi = 0.f;
    if (lane < 32) { xr = b2f(kvc[base + 2 * lane]); xi = b2f(kvc[base + 2 * lane + 1]); }

    float s1 = v0 + v1, s2 = v0 * v0 + v1 * v1;
#pragma unroll
    for (int off = 32; off > 0; off >>= 1) {
        s1 += __shfl_xor(s1, off);
        s2 += __shfl_xor(s2, off);
    }
    const float mu = s1 * (1.f / 128.f);
    const float rinv = rsqrtf(s2 * (1.f / 128.f) - mu * mu + EPSF);
    kvn[(size_t)idx * 128 + lane]      = f2b((v0 - mu) * rinv * knw[lane] + knb[lane]);
    kvn[(size_t)idx * 128 + lane + 64] = f2b((v1 - mu) * rinv * knw[lane + 64] + knb[lane + 64]);

    if (lane < 32) {
        const float freq = exp2f(-0.41524101186092014f * (float)lane); // 10000^(-2l/64)
        const float ang = (float)s * freq;
        float sn, c; sincosf(ang, &sn, &c);
        kvc[base + 128 + 2 * lane]     = f2b(xr * c - xi * sn);
        kvc[base + 128 + 2 * lane + 1] = f2b(xr * sn + xi * c);
    }
}

// ---------------------------------------------------------------------------
// Elementwise fp32 -> bf16 cast.
// ---------------------------------------------------------------------------
__global__ __launch_bounds__(256) void cast_bf16_k(const float* __restrict__ X,
                                                   bf16* __restrict__ Y, int n4) {
    for (int i = blockIdx.x * 256 + threadIdx.x; i < n4; i += gridDim.x * 256) {
        const f32x4 v = ((const f32x4*)X)[i];
        short4v o;
#pragma unroll
        for (int j = 0; j < 4; j++) {
            bf16 b = f2b(v[j]);
            o[j] = *(short*)&b;
        }
        ((short4v*)Y)[i] = o;
    }
}

// ---------------------------------------------------------------------------
// Tiled transpose-cast: W (KxN fp32) -> Wt (NxK bf16).
// ---------------------------------------------------------------------------
__global__ __launch_bounds__(256) void transpose_cast_k(const float* __restrict__ W,
                                                        bf16* __restrict__ Wt,
                                                        int K, int N) {
    __shared__ float tile[32][33];
    const int t = threadIdx.x;
    const int tx = t & 31, ty = t >> 5;
    const int n0 = blockIdx.x * 32;
    const int k0 = blockIdx.y * 32;
#pragma unroll
    for (int i = 0; i < 4; i++)
        tile[ty + 8 * i][tx] = W[(size_t)(k0 + ty + 8 * i) * N + n0 + tx];
    __syncthreads();
#pragma unroll
    for (int i = 0; i < 4; i++)
        Wt[(size_t)(n0 + ty + 8 * i) * K + k0 + tx] = f2b(tile[tx][ty + 8 * i]);
}

// ---------------------------------------------------------------------------
// Row layernorm emitting bf16.
// ---------------------------------------------------------------------------
__global__ __launch_bounds__(256) void layernorm_cast_k(const float* __restrict__ X,
                                                        const float* __restrict__ w,
                                                        const float* __restrict__ b,
                                                        bf16* __restrict__ Y,
                                                        int L) {
    __shared__ float r1[256], r2[256];
    const int row = blockIdx.x;
    const int t = threadIdx.x;
    const float* xp = X + (size_t)row * L;
    bf16* yp = Y + (size_t)row * L;
    float s1 = 0.f, s2 = 0.f;
    for (int j = t; j < L; j += 256) { const float v = xp[j]; s1 += v; s2 += v * v; }
    r1[t] = s1; r2[t] = s2; __syncthreads();
    for (int off = 128; off > 0; off >>= 1) {
        if (t < off) { r1[t] += r1[t + off]; r2[t] += r2[t + off]; }
        __syncthreads();
    }
    const float mu   = r1[0] / (float)L;
    const float var  = r2[0] / (float)L - mu * mu;
    const float rinv = rsqrtf(var + EPSF);
    for (int j = t; j < L; j += 256)
        yp[j] = f2b((xp[j] - mu) * rinv * w[j] + b[j]);
}

// ---------------------------------------------------------------------------
// Sparse branch v3: top-k (unchanged) + BATCHED sel computation. All 8
// selected x rows staged in LDS (64 KB), then ONE sweep over the block's
// 1 MB W_ip column-slice with 8 accumulators/thread (32 FMA per 16B W load).
// Fixes R10's regression: per-block W traffic 8 MB -> 1 MB.
// ---------------------------------------------------------------------------
__global__ __launch_bounds__(256) void sparse_k(const float* __restrict__ gate,
                                                const float* __restrict__ x,
                                                const float* __restrict__ Wip,
                                                const float* __restrict__ Wsq,
                                                const float* __restrict__ Wsk,
                                                const float* __restrict__ Wsv,
                                                const float* __restrict__ Wio,
                                                float* __restrict__ io) {
    __shared__ float g[S_];
    __shared__ float xr8[TOPK][H_];     // 64 KB: the 8 selected x rows
    __shared__ float sel[TOPK][ID];
    __shared__ float sq[TOPK][ID], sk[TOPK][ID], sv[TOPK][ID];
    __shared__ float sp[TOPK][TOPK];
    __shared__ float ms[ID];
    __shared__ float rv[256];
    __shared__ int ri[256];
    __shared__ int sidx[TOPK];
    const int bi = blockIdx.x;
    const int ih = bi % IH;
    const int b = bi / IH;
    const int t = threadIdx.x;

    for (int s = t; s < S_; s += 256) g[s] = gate[(size_t)(b * S_ + s) * IH + ih];
    __syncthreads();

    for (int r = 0; r < TOPK; r++) {
        float bv = -INFINITY; int bx = S_;
        for (int s = t; s < S_; s += 256) {
            const float v = g[s];
            if (v > bv) { bv = v; bx = s; }
        }
        rv[t] = bv; ri[t] = bx; __syncthreads();
        for (int off = 128; off > 0; off >>= 1) {
            if (t < off) {
                const float v2 = rv[t + off]; const int i2 = ri[t + off];
                if (v2 > rv[t] || (v2 == rv[t] && i2 < ri[t])) { rv[t] = v2; ri[t] = i2; }
            }
            __syncthreads();
        }
        if (t == 0) { sidx[r] = ri[0]; g[ri[0]] = -INFINITY; }
        __syncthreads();
    }

    // Stage all 8 selected rows (f32x4 vectorized).
    for (int r = 0; r < TOPK; r++) {
        const f32x4* xrow = (const f32x4*)(x + ((size_t)b * S_ + sidx[r]) * H_);
        for (int k4 = t; k4 < H_ / 4; k4 += 256)
            *(f32x4*)&xr8[r][k4 * 4] = xrow[k4];
    }
    __syncthreads();

    // sel[r][n] = sum_k xr8[r][k] * Wip[k, ih*ID+n], one W sweep, 8-row batch.
    {
        const int n4 = (t & 31) * 4;          // col base 0..124
        const int kc = (t >> 5) * 256;        // k chunk base
        f32x4 aa[8];
#pragma unroll
        for (int r = 0; r < 8; r++) aa[r] = (f32x4){0.f, 0.f, 0.f, 0.f};
        for (int k = 0; k < 256; k++) {
            const f32x4 wv = *(const f32x4*)&Wip[(size_t)(kc + k) * (IH * ID) + ih * ID + n4];
#pragma unroll
            for (int r = 0; r < 8; r++) {
                const float xv = xr8[r][kc + k];
#pragma unroll
                for (int e = 0; e < 4; e++) aa[r][e] += xv * wv[e];
            }
        }
        float* sc = &sq[0][0];                // 1024-float scratch
#pragma unroll
        for (int r = 0; r < 8; r++) {
            *(f32x4*)&sc[(t >> 5) * 128 + n4] = aa[r];
            __syncthreads();
            if (t < ID) {
                float a = 0.f;
#pragma unroll
                for (int c = 0; c < 8; c++) a += sc[c * 128 + t];
                sel[r][t] = a;
            }
            __syncthreads();
        }
    }

    for (int i = t; i < TOPK * ID; i += 256) {
        const int r = i >> 7, n = i & 127;
        float aq = 0.f, ak = 0.f, av = 0.f;
        for (int k = 0; k < 128; k++) {
            const float s = sel[r][k];
            aq += s * Wsq[k * ID + n];
            ak += s * Wsk[k * ID + n];
            av += s * Wsv[k * ID + n];
        }
        sq[r][n] = aq; sk[r][n] = ak; sv[r][n] = av;
    }
    __syncthreads();

    if (t < TOPK * TOPK) {
        const int r = t >> 3, c = t & 7;
        float a = 0.f;
        for (int k = 0; k < 128; k++) a += sq[r][k] * sk[c][k];
        sp[r][c] = a * 0.08838834764831845f;
    }
    __syncthreads();

    if (t < TOPK) {
        float m = -INFINITY;
        for (int c = 0; c < 8; c++) m = fmaxf(m, sp[t][c]);
        float e[8]; float sum = 0.f;
        for (int c = 0; c < 8; c++) { e[c] = expf(sp[t][c] - m); sum += e[c]; }
        for (int c = 0; c < 8; c++) sp[t][c] = e[c] / sum;
    }
    __syncthreads();

    if (t < ID) {
        float acc = 0.f;
        for (int r = 0; r < 8; r++) {
            float so = 0.f;
            for (int c = 0; c < 8; c++) so += sp[r][c] * sv[c][t];
            acc += so;
        }
        ms[t] = acc * 0.125f;
    }
    __syncthreads();

    if (t < ID) {
        float acc = 0.f;
        for (int k = 0; k < 128; k++) acc += ms[k] * Wio[(size_t)k * H_ + t];
        io[((size_t)b * IH + ih) * ID + t] = acc;
    }
}

// ---------------------------------------------------------------------------
// MFMA flash attention v6 (verified R8): one q-tile per block, heavy-first
// dispatch, pipeline staging, defer-max, (256,2) bounds.
// ---------------------------------------------------------------------------
__global__ __launch_bounds__(256, 2) void attn_mfma_k(const bf16* __restrict__ Qp,
                                                      const bf16* __restrict__ Kc,
                                                      const bf16* __restrict__ VbT,
                                                      const float* __restrict__ io,
                                                      bf16* __restrict__ O) {
    __shared__ unsigned short Kt[64 * 200];
    __shared__ unsigned short Vt[128 * 72];
    __shared__ unsigned short Ps[4 * 16 * 72];

    const int lin = blockIdx.x;
    const int qt = 31 - (lin >> 5);            // heavy-first
    const int hb = lin & 31;
    const int h = hb & 15;
    const int b = hb >> 4;
    const int q0 = qt * 64;

    const int t = threadIdx.x;
    const int lane = t & 63;
    const int wq = t >> 6;
    const int col = lane & 15;
    const int quad = lane >> 4;

    const float scale = 0.07216878364870322f;  // 1/sqrt(192)
    const bf16* vplane = VbT + (size_t)(b * NH + h) * 128 * (size_t)S_;

    const int kr = t >> 2;
    const int kc0 = (t & 3) * 48;
    const int vki0 = (t & 7) * 8;
    const int vdv = t >> 3;

    short8 qfrag[6];
    {
        const int q = q0 + wq * 16 + col;
        const short8* qrow = (const short8*)(Qp + ((size_t)(b * S_ + q) * NH + h) * 192);
#pragma unroll
        for (int kc = 0; kc < 6; kc++) qfrag[kc] = qrow[kc * 4 + quad];
    }

    float m_r[4], l_r[4];
#pragma unroll
    for (int r = 0; r < 4; r++) { m_r[r] = -1e30f; l_r[r] = 0.f; }
    f32x4 accO[8];
#pragma unroll
    for (int nt = 0; nt < 8; nt++) accO[nt] = (f32x4){0.f, 0.f, 0.f, 0.f};

    const int nkt = qt + 1;

    short8 kreg[6], vreg[4];
    {
        const short8* ksrc = (const short8*)(Kc + ((size_t)(b * S_ + kr) * NH + h) * 192 + kc0);
#pragma unroll
        for (int c = 0; c < 6; c++) kreg[c] = ksrc[c];
#pragma unroll
        for (int p = 0; p < 4; p++)
            vreg[p] = *(const short8*)(vplane + (size_t)(p * 32 + vdv) * S_ + vki0);
    }

    for (int kt = 0; kt < nkt; kt++) {
        const int kt0 = kt * 64;
        __syncthreads();
        {
            short8* dst = (short8*)&Kt[kr * 200 + kc0];
#pragma unroll
            for (int c = 0; c < 6; c++) dst[c] = kreg[c];
#pragma unroll
            for (int p = 0; p < 4; p++)
                *(short8*)&Vt[(p * 32 + vdv) * 72 + vki0] = vreg[p];
        }
        __syncthreads();

        if (kt + 1 < nkt) {
            const int nk0 = kt0 + 64;
            const short8* ksrc = (const short8*)(Kc + ((size_t)(b * S_ + nk0 + kr) * NH + h) * 192 + kc0);
#pragma unroll
            for (int c = 0; c < 6; c++) kreg[c] = ksrc[c];
#pragma unroll
            for (int p = 0; p < 4; p++)
                vreg[p] = *(const short8*)(vplane + (size_t)(p * 32 + vdv) * S_ + nk0 + vki0);
        }

        f32x4 s[4];
        __builtin_amdgcn_s_setprio(1);
#pragma unroll
        for (int nt = 0; nt < 4; nt++) {
            f32x4 acc = (f32x4){0.f, 0.f, 0.f, 0.f};
#pragma unroll
            for (int kc = 0; kc < 6; kc++) {
                const short8 kf = *(const short8*)&Kt[(nt * 16 + col) * 200 + kc * 32 + quad * 8];
                acc = __builtin_amdgcn_mfma_f32_16x16x32_bf16(qfrag[kc], kf, acc, 0, 0, 0);
            }
            s[nt] = acc;
        }
        __builtin_amdgcn_s_setprio(0);
#pragma unroll
        for (int nt = 0; nt < 4; nt++)
#pragma unroll
            for (int r = 0; r < 4; r++) {
                const int kg = kt0 + nt * 16 + col;
                const int qg = q0 + wq * 16 + quad * 4 + r;
                const float v = s[nt][r] * scale;
                s[nt][r] = (kg > qg) ? -1e30f : v;
            }
        float alpha[4];
#pragma unroll
        for (int r = 0; r < 4; r++) {
            float mt = fmaxf(fmaxf(s[0][r], s[1][r]), fmaxf(s[2][r], s[3][r]));
            mt = fmaxf(mt, __shfl_xor(mt, 1));
            mt = fmaxf(mt, __shfl_xor(mt, 2));
            mt = fmaxf(mt, __shfl_xor(mt, 4));
            mt = fmaxf(mt, __shfl_xor(mt, 8));
            const bool need = (mt > m_r[r] + 8.f);
            const float mn = need ? mt : m_r[r];
            alpha[r] = need ? __expf(m_r[r] - mn) : 1.f;
            m_r[r] = mn;
            float rs = 0.f;
#pragma unroll
            for (int nt = 0; nt < 4; nt++) {
                const float p = __expf(s[nt][r] - mn);
                s[nt][r] = p;
                rs += p;
            }
            rs += __shfl_xor(rs, 1);
            rs += __shfl_xor(rs, 2);
            rs += __shfl_xor(rs, 4);
            rs += __shfl_xor(rs, 8);
            l_r[r] = l_r[r] * alpha[r] + rs;
        }
        {
            unsigned short* pw = &Ps[wq * 1152];
#pragma unroll
            for (int nt = 0; nt < 4; nt++)
#pragma unroll
                for (int r = 0; r < 4; r++) {
                    bf16 hv = f2b(s[nt][r]);
                    pw[(quad * 4 + r) * 72 + nt * 16 + col] = *(unsigned short*)&hv;
                }
        }
        short8 pf[2];
#pragma unroll
        for (int kk = 0; kk < 2; kk++)
            pf[kk] = *(const short8*)&Ps[wq * 1152 + col * 72 + kk * 32 + quad * 8];
        if (!(alpha[0] == 1.f && alpha[1] == 1.f && alpha[2] == 1.f && alpha[3] == 1.f)) {
#pragma unroll
            for (int nt = 0; nt < 8; nt++)
#pragma unroll
                for (int r = 0; r < 4; r++) accO[nt][r] *= alpha[r];
        }
        __builtin_amdgcn_s_setprio(1);
#pragma unroll
        for (int nt = 0; nt < 8; nt++) {
#pragma unroll
            for (int kk = 0; kk < 2; kk++) {
                const short8 vf = *(const short8*)&Vt[(nt * 16 + col) * 72 + kk * 32 + quad * 8];
                accO[nt] = __builtin_amdgcn_mfma_f32_16x16x32_bf16(pf[kk], vf, accO[nt], 0, 0, 0);
            }
        }
        __builtin_amdgcn_s_setprio(0);
    }

    const float* iorow = io + ((size_t)b * IH + (h >> 1)) * ID;
    float rinv[4];
#pragma unroll
    for (int r = 0; r < 4; r++) rinv[r] = 1.f / l_r[r];
#pragma unroll
    for (int nt = 0; nt < 8; nt++) {
        const int dv = nt * 16 + col;
        const float iov = iorow[dv];
#pragma unroll
        for (int r = 0; r < 4; r++) {
            const int q = q0 + wq * 16 + quad * 4 + r;
            O[((size_t)(b * S_ + q) * NH + h) * VD + dv] = f2b(accO[nt][r] * rinv[r] + iov);
        }
    }
}

// ---------------------------------------------------------------------------
// Workspace timeline (all slots within proven ~100.8 MB):
//  S0 = ws+0       (33.5MB): WtM(18.9) -> cqb(12.6)+WqT(9.4 @+12.6M)
//                            -> kvn(16.8) -> attnb(16.8)+WoT(8.4 @+16.8M)
//  S1 = ws+32MB    (25.2MB): cq fp32 (25.2) -> qp bf16 (25.2)
//  S2 = ws+56MB    (25.2MB): kvc
//  S3 = ws+80MB    (16.8MB): VbT
//  S4 = ws+96MB    (131KB) : gate -> WkvT
//  S5 = ws+96MB+128KB      : iob
//  xb lives in d_out (dead after gemm_x2; out written last).
// ---------------------------------------------------------------------------
extern "C" void kernel_launch(void* const* d_in, const int* in_sizes, int n_in,
                              void* d_out, int out_size, void* d_ws, size_t ws_size,
                              hipStream_t stream) {
    const float* x      = (const float*)d_in[0];
    const float* W_cq   = (const float*)d_in[1];
    const float* qn_w   = (const float*)d_in[2];
    const float* qn_b   = (const float*)d_in[3];
    const float* W_q    = (const float*)d_in[4];
    const float* W_ckv  = (const float*)d_in[5];
    const float* kvn_w  = (const float*)d_in[6];
    const float* kvn_b  = (const float*)d_in[7];
    const float* W_kv   = (const float*)d_in[8];
    const float* W_o    = (const float*)d_in[9];
    const float* W_ip   = (const float*)d_in[10];
    const float* W_ig   = (const float*)d_in[11];
    const float* W_sq   = (const float*)d_in[12];
    const float* W_sk   = (const float*)d_in[13];
    const float* W_sv   = (const float*)d_in[14];
    const float* W_io   = (const float*)d_in[15];
    float* out = (float*)d_out;

    const int M = B_ * S_;

    char* wsb = (char*)d_ws;
    // S0 tenants
    bf16*  WtM   = (bf16*)wsb;                       // merged x-proj weights^T (18.9MB)
    bf16*  cqb   = (bf16*)wsb;                       // bf16 LN output (12.6MB)
    bf16*  WqT   = (bf16*)(wsb + 12582912);          // W_q^T (9.4MB)
    bf16*  kvn   = (bf16*)wsb;                       // LN'd kv_nope (16.8MB)
    bf16*  attnb = (bf16*)wsb;                       // attention out bf16 (16.8MB)
    bf16*  WoT   = (bf16*)(wsb + 16777216);          // W_o^T (8.4MB)
    // S1
    float* cq    = (float*)(wsb + 33554432);
    bf16*  qp    = (bf16*)(wsb + 33554432);
    // S2
    bf16*  kvc   = (bf16*)(wsb + 58720256);
    // S3
    bf16*  VbT   = (bf16*)(wsb + 83886080);
    // S4/S5
    float* gate  = (float*)(wsb + 100663296);
    bf16*  WkvT  = (bf16*)(wsb + 100663296);
    float* iob   = (float*)(wsb + 100794368);
    bf16*  xb    = (bf16*)d_out;

    dim3 blk(256);

    // 1. cast x -> bf16
    cast_bf16_k<<<dim3(2048), blk, 0, stream>>>(x, xb, M * H_ / 4);

    // 2. merged weight transposes: WtM rows [0,1536) = W_cq^T, [1536,4608) = W_ckv^T
    transpose_cast_k<<<dim3(QLR / 32, H_ / 32), blk, 0, stream>>>(W_cq, WtM, H_, QLR);
    transpose_cast_k<<<dim3(3072 / 32, H_ / 32), blk, 0, stream>>>(W_ckv, WtM + (size_t)1536 * H_, H_, 3072);

    // 3. merged GEMM: cq | kvc
    gemm_x2_k<<<dim3(4608 / 128, M / 128), blk, 0, stream>>>(xb, WtM, cq, kvc);

    // 4. LN -> cqb (frees WtM)
    layernorm_cast_k<<<dim3(M), blk, 0, stream>>>(cq, qn_w, qn_b, cqb, QLR);

    // 5-6. qp = cqb @ W_q with fused RoPE (cq dead -> qp in S1)
    transpose_cast_k<<<dim3(3072 / 32, QLR / 32), blk, 0, stream>>>(W_q, WqT, QLR, 3072);
    gemm_q_rope_k<<<dim3(3072 / 128, M / 128), blk, 0, stream>>>(cqb, WqT, qp);

    // 7. gate = x @ W_ig — EXACT fp32
    gate_k<<<dim3(M / 4), blk, 0, stream>>>(x, W_ig, gate);

    // 8. kv LN (cqb/WqT dead -> kvn in S0)
    kv_ln_k<<<dim3(B_ * S_ * NH / 4), blk, 0, stream>>>(kvc, kvn_w, kvn_b, kvn);

    // 9. sparse branch v3: top-k + batched sel (one W_ip sweep per block)
    sparse_k<<<dim3(B_ * IH), blk, 0, stream>>>(gate, x, W_ip, W_sq, W_sk, W_sv, W_io, iob);

    // 10-11. kv matmul (gate dead -> WkvT)
    transpose_cast_k<<<dim3(256 / 32, 128 / 32), blk, 0, stream>>>(W_kv, WkvT, 128, 256);
    gemm_kv_k<<<dim3(2, (B_ * S_ * NH) / 128), blk, 0, stream>>>(kvn, WkvT, kvc, VbT);

    // 12. attention, heavy-first single-tile grid (kvn dead -> attnb in S0)
    attn_mfma_k<<<dim3(1024), blk, 0, stream>>>(qp, kvc, VbT, iob, attnb);

    // 13-14. out = attnb @ W_o
    transpose_cast_k<<<dim3(H_ / 32, H_ / 32), blk, 0, stream>>>(W_o, WoT, H_, H_);
    gemm_bt_mfma_k<float><<<dim3(H_ / 128, M / 128), blk, 0, stream>>>(attnb, WoT, out, M, H_, H_);
}

// Round 12
// 675.468 us; speedup vs baseline: 1.1641x; 1.1209x over previous
//
#include <hip/hip_runtime.h>
#include <hip/hip_bf16.h>
#include <math.h>

// Problem constants
#define NH    16
#define NOPE  128
#define ROPED 64
#define VD    128
#define QLR   1536
#define IH    8
#define ID    128
#define TOPK  8
#define EPSF  1e-5f
#define B_    2
#define S_    2048
#define H_    2048

using bf16 = __hip_bfloat16;
typedef __attribute__((ext_vector_type(8))) short short8;
typedef __attribute__((ext_vector_type(4))) short short4v;
typedef __attribute__((ext_vector_type(4))) float f32x4;

#define GLOBAL_AS __attribute__((address_space(1)))
#define LDS_AS    __attribute__((address_space(3)))

__device__ __forceinline__ float b2f(bf16 v) { return __bfloat162float(v); }
__device__ __forceinline__ bf16 f2b(float v) { return __float2bfloat16(v); }
__device__ __forceinline__ void stoC(float* p, float v) { *p = v; }
__device__ __forceinline__ void stoC(bf16* p, float v) { *p = __float2bfloat16(v); }

// ---------------------------------------------------------------------------
// Dedicated gate projection (exact fp32, verified R4).
// ---------------------------------------------------------------------------
__global__ __launch_bounds__(256) void gate_k(const float* __restrict__ x,
                                              const float* __restrict__ Wg,
                                              float* __restrict__ gate) {
    const int t = threadIdx.x;
    const int wid = t >> 6, lane = t & 63;
    const int row = blockIdx.x * 4 + wid;
    const float* xp = x + (size_t)row * H_;

    float acc[8] = {};
    for (int k0 = 0; k0 < H_; k0 += 256) {
        const int kb = k0 + lane * 4;
        const f32x4 xv = *(const f32x4*)(xp + kb);
        const f32x4 w0 = *(const f32x4*)(Wg + (size_t)kb * 8);
        const f32x4 w1 = *(const f32x4*)(Wg + (size_t)kb * 8 + 4);
        const f32x4 w2 = *(const f32x4*)(Wg + (size_t)(kb + 1) * 8);
        const f32x4 w3 = *(const f32x4*)(Wg + (size_t)(kb + 1) * 8 + 4);
        const f32x4 w4 = *(const f32x4*)(Wg + (size_t)(kb + 2) * 8);
        const f32x4 w5 = *(const f32x4*)(Wg + (size_t)(kb + 2) * 8 + 4);
        const f32x4 w6 = *(const f32x4*)(Wg + (size_t)(kb + 3) * 8);
        const f32x4 w7 = *(const f32x4*)(Wg + (size_t)(kb + 3) * 8 + 4);
#pragma unroll
        for (int j = 0; j < 4; j++) {
            acc[j]     += xv[0] * w0[j] + xv[1] * w2[j] + xv[2] * w4[j] + xv[3] * w6[j];
            acc[4 + j] += xv[0] * w1[j] + xv[1] * w3[j] + xv[2] * w5[j] + xv[3] * w7[j];
        }
    }
#pragma unroll
    for (int j = 0; j < 8; j++) {
#pragma unroll
        for (int off = 32; off > 0; off >>= 1)
            acc[j] += __shfl_xor(acc[j], off);
    }
    if (lane == 0) {
#pragma unroll
        for (int j = 0; j < 8; j++) gate[(size_t)row * 8 + j] = acc[j];
    }
}

// ---------------------------------------------------------------------------
// bf16 MFMA GEMM, m97 structure + bijective chunked XCD swizzle.
// ---------------------------------------------------------------------------
template <typename OT>
__global__ __launch_bounds__(256) void gemm_bt_mfma_k(const bf16* __restrict__ A,
                                                      const bf16* __restrict__ Bt,
                                                      OT* __restrict__ C,
                                                      int M, int N, int K) {
    __shared__ bf16 As[128 * 32];
    __shared__ bf16 Bs[128 * 32];
    const int t = threadIdx.x;
    const int w = t >> 6;
    const int l = t & 63;
    const int col = l & 15;
    const int quad = l >> 4;
    const int wm = w >> 1, wn = w & 1;

    const int gx = gridDim.x;
    const int nwg = gx * gridDim.y;
    const int lin = blockIdx.y * gx + blockIdx.x;
    const int work = (lin & 7) * (nwg >> 3) + (lin >> 3);
    const int row0 = (work / gx) * 128;
    const int col0 = (work % gx) * 128;

    const int rA = l >> 2;
    const int cA = (l & 3) * 8;
    const bf16* ga0 = A + (size_t)(row0 + w * 16 + rA) * K + cA;
    const bf16* ga1 = A + (size_t)(row0 + (4 + w) * 16 + rA) * K + cA;
    const bf16* gb0 = Bt + (size_t)(col0 + w * 16 + rA) * K + cA;
    const bf16* gb1 = Bt + (size_t)(col0 + (4 + w) * 16 + rA) * K + cA;
    bf16* lA0 = &As[w * 512];
    bf16* lA1 = &As[(4 + w) * 512];
    bf16* lB0 = &Bs[w * 512];
    bf16* lB1 = &Bs[(4 + w) * 512];

    f32x4 acc[4][4];
#pragma unroll
    for (int i = 0; i < 4; i++)
#pragma unroll
        for (int j = 0; j < 4; j++) acc[i][j] = (f32x4){0.f, 0.f, 0.f, 0.f};

    for (int k0 = 0; k0 < K; k0 += 32) {
        __syncthreads();
        __builtin_amdgcn_global_load_lds((const GLOBAL_AS void*)(ga0 + k0),
                                         (LDS_AS void*)lA0, 16, 0, 0);
        __builtin_amdgcn_global_load_lds((const GLOBAL_AS void*)(ga1 + k0),
                                         (LDS_AS void*)lA1, 16, 0, 0);
        __builtin_amdgcn_global_load_lds((const GLOBAL_AS void*)(gb0 + k0),
                                         (LDS_AS void*)lB0, 16, 0, 0);
        __builtin_amdgcn_global_load_lds((const GLOBAL_AS void*)(gb1 + k0),
                                         (LDS_AS void*)lB1, 16, 0, 0);
        __syncthreads();

        short8 af[4], bfr[4];
#pragma unroll
        for (int i = 0; i < 4; i++) {
            af[i]  = *(const short8*)&As[(wm * 64 + i * 16 + col) * 32 + quad * 8];
            bfr[i] = *(const short8*)&Bs[(wn * 64 + i * 16 + col) * 32 + quad * 8];
        }
#pragma unroll
        for (int i = 0; i < 4; i++)
#pragma unroll
            for (int j = 0; j < 4; j++)
                acc[i][j] = __builtin_amdgcn_mfma_f32_16x16x32_bf16(af[i], bfr[j], acc[i][j], 0, 0, 0);
    }

#pragma unroll
    for (int i = 0; i < 4; i++)
#pragma unroll
        for (int j = 0; j < 4; j++)
#pragma unroll
            for (int r = 0; r < 4; r++) {
                const int gr = row0 + wm * 64 + i * 16 + quad * 4 + r;
                const int gc = col0 + wn * 64 + j * 16 + col;
                stoC(C + (size_t)gr * N + gc, acc[i][j][r]);
            }
}

// ---------------------------------------------------------------------------
// Merged x-projection GEMM (cq | kvc only). N = 4608: rows [0,1536) =
// W_cq^T, [1536,4608) = W_ckv^T. Routing block-uniform.
// ---------------------------------------------------------------------------
__global__ __launch_bounds__(256) void gemm_x2_k(const bf16* __restrict__ A,
                                                 const bf16* __restrict__ Bt,
                                                 float* __restrict__ cq,
                                                 bf16* __restrict__ kvc) {
    __shared__ bf16 As[128 * 32];
    __shared__ bf16 Bs[128 * 32];
    const int K = H_;
    const int t = threadIdx.x;
    const int w = t >> 6;
    const int l = t & 63;
    const int col = l & 15;
    const int quad = l >> 4;
    const int wm = w >> 1, wn = w & 1;

    const int gx = gridDim.x;
    const int nwg = gx * gridDim.y;
    const int lin = blockIdx.y * gx + blockIdx.x;
    const int work = (lin & 7) * (nwg >> 3) + (lin >> 3);
    const int row0 = (work / gx) * 128;
    const int col0 = (work % gx) * 128;

    const int rA = l >> 2;
    const int cA = (l & 3) * 8;
    const bf16* ga0 = A + (size_t)(row0 + w * 16 + rA) * K + cA;
    const bf16* ga1 = A + (size_t)(row0 + (4 + w) * 16 + rA) * K + cA;
    const bf16* gb0 = Bt + (size_t)(col0 + w * 16 + rA) * K + cA;
    const bf16* gb1 = Bt + (size_t)(col0 + (4 + w) * 16 + rA) * K + cA;
    bf16* lA0 = &As[w * 512];
    bf16* lA1 = &As[(4 + w) * 512];
    bf16* lB0 = &Bs[w * 512];
    bf16* lB1 = &Bs[(4 + w) * 512];

    f32x4 acc[4][4];
#pragma unroll
    for (int i = 0; i < 4; i++)
#pragma unroll
        for (int j = 0; j < 4; j++) acc[i][j] = (f32x4){0.f, 0.f, 0.f, 0.f};

    for (int k0 = 0; k0 < K; k0 += 32) {
        __syncthreads();
        __builtin_amdgcn_global_load_lds((const GLOBAL_AS void*)(ga0 + k0),
                                         (LDS_AS void*)lA0, 16, 0, 0);
        __builtin_amdgcn_global_load_lds((const GLOBAL_AS void*)(ga1 + k0),
                                         (LDS_AS void*)lA1, 16, 0, 0);
        __builtin_amdgcn_global_load_lds((const GLOBAL_AS void*)(gb0 + k0),
                                         (LDS_AS void*)lB0, 16, 0, 0);
        __builtin_amdgcn_global_load_lds((const GLOBAL_AS void*)(gb1 + k0),
                                         (LDS_AS void*)lB1, 16, 0, 0);
        __syncthreads();

        short8 af[4], bfr[4];
#pragma unroll
        for (int i = 0; i < 4; i++) {
            af[i]  = *(const short8*)&As[(wm * 64 + i * 16 + col) * 32 + quad * 8];
            bfr[i] = *(const short8*)&Bs[(wn * 64 + i * 16 + col) * 32 + quad * 8];
        }
#pragma unroll
        for (int i = 0; i < 4; i++)
#pragma unroll
            for (int j = 0; j < 4; j++)
                acc[i][j] = __builtin_amdgcn_mfma_f32_16x16x32_bf16(af[i], bfr[j], acc[i][j], 0, 0, 0);
    }

#pragma unroll
    for (int i = 0; i < 4; i++)
#pragma unroll
        for (int j = 0; j < 4; j++)
#pragma unroll
            for (int r = 0; r < 4; r++) {
                const int gr = row0 + wm * 64 + i * 16 + quad * 4 + r;
                const int gc = col0 + wn * 64 + j * 16 + col;
                const float v = acc[i][j][r];
                if (col0 < 1536) cq[(size_t)gr * QLR + gc] = v;
                else             kvc[(size_t)gr * 3072 + (gc - 1536)] = f2b(v);
            }
}

// ---------------------------------------------------------------------------
// kv matmul on MFMA (verified R5). col-block 0 -> kvc k_nope; col-block 1 ->
// VbT[bh][dv][s] packed 8B stores.
// ---------------------------------------------------------------------------
__global__ __launch_bounds__(256) void gemm_kv_k(const bf16* __restrict__ A,
                                                 const bf16* __restrict__ Bt,
                                                 bf16* __restrict__ kvc,
                                                 bf16* __restrict__ VbT) {
    __shared__ bf16 As[128 * 32];
    __shared__ bf16 Bs[128 * 32];
    const int K = 128;
    const int t = threadIdx.x;
    const int w = t >> 6;
    const int l = t & 63;
    const int col = l & 15;
    const int quad = l >> 4;
    const int wm = w >> 1, wn = w & 1;

    const int gx = gridDim.x;
    const int nwg = gx * gridDim.y;
    const int lin = blockIdx.y * gx + blockIdx.x;
    const int work = (lin & 7) * (nwg >> 3) + (lin >> 3);
    const int row0 = (work / gx) * 128;
    const int col0 = (work % gx) * 128;

    const int rA = l >> 2;
    const int cA = (l & 3) * 8;
    const bf16* ga0 = A + (size_t)(row0 + w * 16 + rA) * K + cA;
    const bf16* ga1 = A + (size_t)(row0 + (4 + w) * 16 + rA) * K + cA;
    const bf16* gb0 = Bt + (size_t)(col0 + w * 16 + rA) * K + cA;
    const bf16* gb1 = Bt + (size_t)(col0 + (4 + w) * 16 + rA) * K + cA;
    bf16* lA0 = &As[w * 512];
    bf16* lA1 = &As[(4 + w) * 512];
    bf16* lB0 = &Bs[w * 512];
    bf16* lB1 = &Bs[(4 + w) * 512];

    f32x4 acc[4][4];
#pragma unroll
    for (int i = 0; i < 4; i++)
#pragma unroll
        for (int j = 0; j < 4; j++) acc[i][j] = (f32x4){0.f, 0.f, 0.f, 0.f};

    for (int k0 = 0; k0 < K; k0 += 32) {
        __syncthreads();
        __builtin_amdgcn_global_load_lds((const GLOBAL_AS void*)(ga0 + k0),
                                         (LDS_AS void*)lA0, 16, 0, 0);
        __builtin_amdgcn_global_load_lds((const GLOBAL_AS void*)(ga1 + k0),
                                         (LDS_AS void*)lA1, 16, 0, 0);
        __builtin_amdgcn_global_load_lds((const GLOBAL_AS void*)(gb0 + k0),
                                         (LDS_AS void*)lB0, 16, 0, 0);
        __builtin_amdgcn_global_load_lds((const GLOBAL_AS void*)(gb1 + k0),
                                         (LDS_AS void*)lB1, 16, 0, 0);
        __syncthreads();

        short8 af[4], bfr[4];
#pragma unroll
        for (int i = 0; i < 4; i++) {
            af[i]  = *(const short8*)&As[(wm * 64 + i * 16 + col) * 32 + quad * 8];
            bfr[i] = *(const short8*)&Bs[(wn * 64 + i * 16 + col) * 32 + quad * 8];
        }
#pragma unroll
        for (int i = 0; i < 4; i++)
#pragma unroll
            for (int j = 0; j < 4; j++)
                acc[i][j] = __builtin_amdgcn_mfma_f32_16x16x32_bf16(af[i], bfr[j], acc[i][j], 0, 0, 0);
    }

    if (col0 == 0) {
#pragma unroll
        for (int i = 0; i < 4; i++)
#pragma unroll
            for (int j = 0; j < 4; j++)
#pragma unroll
                for (int r = 0; r < 4; r++) {
                    const int gr = row0 + wm * 64 + i * 16 + quad * 4 + r;
                    const int gc = wn * 64 + j * 16 + col;
                    kvc[(size_t)gr * 192 + gc] = f2b(acc[i][j][r]);
                }
    } else {
        const int bb = row0 >> 15;
        const int ssb = ((row0 >> 4) & (S_ - 1)) + wm * 4;
#pragma unroll
        for (int j = 0; j < 4; j++) {
            const int dv = wn * 64 + j * 16 + col;
#pragma unroll
            for (int r = 0; r < 4; r++) {
                const int hh = quad * 4 + r;
                short4v pk;
#pragma unroll
                for (int i = 0; i < 4; i++) {
                    bf16 v = f2b(acc[i][j][r]);
                    pk[i] = *(short*)&v;
                }
                *(short4v*)&VbT[((size_t)(bb * NH + hh) * 128 + dv) * S_ + ssb] = pk;
            }
        }
    }
}

// ---------------------------------------------------------------------------
// Wave-per-row LN of kv_nope -> bf16 kvn, plus RoPE of k_pe.
// ---------------------------------------------------------------------------
__global__ __launch_bounds__(256) void kv_ln_k(bf16* __restrict__ kvc,
                                               const float* __restrict__ knw,
                                               const float* __restrict__ knb,
                                               bf16* __restrict__ kvn) {
    const int idx = blockIdx.x * 4 + (threadIdx.x >> 6);   // row 0..65535
    const int lane = threadIdx.x & 63;
    const int s = (idx >> 4) & (S_ - 1);
    const size_t base = (size_t)idx * 192;

    const float v0 = b2f(kvc[base + 64 + lane]);
    const float v1 = b2f(kvc[base + 128 + lane]);
    float xr = 0.f, xi = 0.f;
    if (lane < 32) { xr = b2f(kvc[base + 2 * lane]); xi = b2f(kvc[base + 2 * lane + 1]); }

    float s1 = v0 + v1, s2 = v0 * v0 + v1 * v1;
#pragma unroll
    for (int off = 32; off > 0; off >>= 1) {
        s1 += __shfl_xor(s1, off);
        s2 += __shfl_xor(s2, off);
    }
    const float mu = s1 * (1.f / 128.f);
    const float rinv = rsqrtf(s2 * (1.f / 128.f) - mu * mu + EPSF);
    kvn[(size_t)idx * 128 + lane]      = f2b((v0 - mu) * rinv * knw[lane] + knb[lane]);
    kvn[(size_t)idx * 128 + lane + 64] = f2b((v1 - mu) * rinv * knw[lane + 64] + knb[lane + 64]);

    if (lane < 32) {
        const float freq = exp2f(-0.41524101186092014f * (float)lane); // 10000^(-2l/64)
        const float ang = (float)s * freq;
        float sn, c; sincosf(ang, &sn, &c);
        kvc[base + 128 + 2 * lane]     = f2b(xr * c - xi * sn);
        kvc[base + 128 + 2 * lane + 1] = f2b(xr * sn + xi * c);
    }
}

// ---------------------------------------------------------------------------
// Elementwise fp32 -> bf16 cast.
// ---------------------------------------------------------------------------
__global__ __launch_bounds__(256) void cast_bf16_k(const float* __restrict__ X,
                                                   bf16* __restrict__ Y, int n4) {
    for (int i = blockIdx.x * 256 + threadIdx.x; i < n4; i += gridDim.x * 256) {
        const f32x4 v = ((const f32x4*)X)[i];
        short4v o;
#pragma unroll
        for (int j = 0; j < 4; j++) {
            bf16 b = f2b(v[j]);
            o[j] = *(short*)&b;
        }
        ((short4v*)Y)[i] = o;
    }
}

// ---------------------------------------------------------------------------
// Tiled transpose-cast: W (KxN fp32) -> Wt (NxK bf16).
// ---------------------------------------------------------------------------
__global__ __launch_bounds__(256) void transpose_cast_k(const float* __restrict__ W,
                                                        bf16* __restrict__ Wt,
                                                        int K, int N) {
    __shared__ float tile[32][33];
    const int t = threadIdx.x;
    const int tx = t & 31, ty = t >> 5;
    const int n0 = blockIdx.x * 32;
    const int k0 = blockIdx.y * 32;
#pragma unroll
    for (int i = 0; i < 4; i++)
        tile[ty + 8 * i][tx] = W[(size_t)(k0 + ty + 8 * i) * N + n0 + tx];
    __syncthreads();
#pragma unroll
    for (int i = 0; i < 4; i++)
        Wt[(size_t)(n0 + ty + 8 * i) * K + k0 + tx] = f2b(tile[tx][ty + 8 * i]);
}

// ---------------------------------------------------------------------------
// Row layernorm emitting bf16.
// ---------------------------------------------------------------------------
__global__ __launch_bounds__(256) void layernorm_cast_k(const float* __restrict__ X,
                                                        const float* __restrict__ w,
                                                        const float* __restrict__ b,
                                                        bf16* __restrict__ Y,
                                                        int L) {
    __shared__ float r1[256], r2[256];
    const int row = blockIdx.x;
    const int t = threadIdx.x;
    const float* xp = X + (size_t)row * L;
    bf16* yp = Y + (size_t)row * L;
    float s1 = 0.f, s2 = 0.f;
    for (int j = t; j < L; j += 256) { const float v = xp[j]; s1 += v; s2 += v * v; }
    r1[t] = s1; r2[t] = s2; __syncthreads();
    for (int off = 128; off > 0; off >>= 1) {
        if (t < off) { r1[t] += r1[t + off]; r2[t] += r2[t + off]; }
        __syncthreads();
    }
    const float mu   = r1[0] / (float)L;
    const float var  = r2[0] / (float)L - mu * mu;
    const float rinv = rsqrtf(var + EPSF);
    for (int j = t; j < L; j += 256)
        yp[j] = f2b((xp[j] - mu) * rinv * w[j] + b[j]);
}

// ---------------------------------------------------------------------------
// In-place RoPE on qp (restored standalone kernel; verified R4-R8).
// ---------------------------------------------------------------------------
__global__ __launch_bounds__(256) void q_rope_k(bf16* __restrict__ qp) {
    const int total = B_ * S_ * NH * 32;
    for (int p = blockIdx.x * 256 + threadIdx.x; p < total; p += gridDim.x * 256) {
        const int j = p & 31;
        const int row = p >> 5;
        const int sr = row >> 4;
        const int s = sr & (S_ - 1);
        const size_t base = (size_t)row * 192 + 128 + 2 * j;
        const float xr = b2f(qp[base]);
        const float xi = b2f(qp[base + 1]);
        const float freq = exp2f(-0.41524101186092014f * (float)j); // 10000^(-2j/64)
        const float ang = (float)s * freq;
        float sn, c; sincosf(ang, &sn, &c);
        qp[base]     = f2b(xr * c - xi * sn);
        qp[base + 1] = f2b(xr * sn + xi * c);
    }
}

// ---------------------------------------------------------------------------
// NEW: top-k selection only (exact fp32). Grid 16 = (b,ih); writes sidx_buf.
// ---------------------------------------------------------------------------
__global__ __launch_bounds__(256) void topk_k(const float* __restrict__ gate,
                                              int* __restrict__ sidx_buf) {
    __shared__ float g[S_];
    __shared__ float rv[256];
    __shared__ int ri[256];
    const int bi = blockIdx.x;
    const int ih = bi % IH;
    const int b = bi / IH;
    const int t = threadIdx.x;

    for (int s = t; s < S_; s += 256) g[s] = gate[(size_t)(b * S_ + s) * IH + ih];
    __syncthreads();

    for (int r = 0; r < TOPK; r++) {
        float bv = -INFINITY; int bx = S_;
        for (int s = t; s < S_; s += 256) {
            const float v = g[s];
            if (v > bv) { bv = v; bx = s; }
        }
        rv[t] = bv; ri[t] = bx; __syncthreads();
        for (int off = 128; off > 0; off >>= 1) {
            if (t < off) {
                const float v2 = rv[t + off]; const int i2 = ri[t + off];
                if (v2 > rv[t] || (v2 == rv[t] && i2 < ri[t])) { rv[t] = v2; ri[t] = i2; }
            }
            __syncthreads();
        }
        if (t == 0) { sidx_buf[bi * TOPK + r] = ri[0]; g[ri[0]] = -INFINITY; }
        __syncthreads();
    }
}

// ---------------------------------------------------------------------------
// NEW: sel partials at full parallelism. Grid (8 kc, 16 bi) = 128 blocks.
// Block (kc,bi): k-range [kc*256, kc*256+256), all 8 selected rows, all 128
// cols of W_ip slice ih. f32x4 W reads, 8-row batch (32 FMA / 16B).
// sel_part[kc][bi][r][n] += partial dot.
// ---------------------------------------------------------------------------
__global__ __launch_bounds__(256) void sel_k(const int* __restrict__ sidx_buf,
                                             const float* __restrict__ x,
                                             const float* __restrict__ Wip,
                                             float* __restrict__ sel_part) {
    __shared__ float xs[TOPK][256];   // 8 KB
    __shared__ float sc[8 * 128];     // 4 KB reduce scratch
    const int kc = blockIdx.x;        // 0..7
    const int bi = blockIdx.y;        // 0..15
    const int ih = bi % IH;
    const int b = bi / IH;
    const int t = threadIdx.x;

    for (int i = t; i < TOPK * 256; i += 256) {
        const int r = i >> 8, k = i & 255;
        const int row = sidx_buf[bi * TOPK + r];
        xs[r][k] = x[((size_t)(b * S_ + row)) * H_ + kc * 256 + k];
    }
    __syncthreads();

    const int n4 = (t & 31) * 4;      // col base 0..124
    const int kg = t >> 5;            // k subgroup 0..7 (32 k each)
    f32x4 aa[8];
#pragma unroll
    for (int r = 0; r < 8; r++) aa[r] = (f32x4){0.f, 0.f, 0.f, 0.f};
    for (int k = 0; k < 32; k++) {
        const int kk = kg * 32 + k;
        const f32x4 wv = *(const f32x4*)&Wip[(size_t)(kc * 256 + kk) * (IH * ID) + ih * ID + n4];
#pragma unroll
        for (int r = 0; r < 8; r++) {
            const float xv = xs[r][kk];
#pragma unroll
            for (int e = 0; e < 4; e++) aa[r][e] += xv * wv[e];
        }
    }
#pragma unroll
    for (int r = 0; r < 8; r++) {
        *(f32x4*)&sc[kg * 128 + n4] = aa[r];
        __syncthreads();
        if (t < ID) {
            float a = 0.f;
#pragma unroll
            for (int c = 0; c < 8; c++) a += sc[c * 128 + t];
            sel_part[(((size_t)kc * 16 + bi) * TOPK + r) * ID + t] = a;
        }
        __syncthreads();
    }
}

// ---------------------------------------------------------------------------
// Sparse branch v4: consumes sel_part (sums 8 k-chunks), then the small
// matmuls + softmax + io as before. Grid 16.
// ---------------------------------------------------------------------------
__global__ __launch_bounds__(256) void sparse_k(const float* __restrict__ sel_part,
                                                const float* __restrict__ Wsq,
                                                const float* __restrict__ Wsk,
                                                const float* __restrict__ Wsv,
                                                const float* __restrict__ Wio,
                                                float* __restrict__ io) {
    __shared__ float sel[TOPK][ID];
    __shared__ float sq[TOPK][ID], sk[TOPK][ID], sv[TOPK][ID];
    __shared__ float sp[TOPK][TOPK];
    __shared__ float ms[ID];
    const int bi = blockIdx.x;
    const int ih = bi % IH;
    const int b = bi / IH;
    const int t = threadIdx.x;

    for (int i = t; i < TOPK * ID; i += 256) {
        const int r = i >> 7, n = i & 127;
        float a = 0.f;
#pragma unroll
        for (int c = 0; c < 8; c++)
            a += sel_part[(((size_t)c * 16 + bi) * TOPK + r) * ID + n];
        sel[r][n] = a;
    }
    __syncthreads();

    for (int i = t; i < TOPK * ID; i += 256) {
        const int r = i >> 7, n = i & 127;
        float aq = 0.f, ak = 0.f, av = 0.f;
        for (int k = 0; k < 128; k++) {
            const float s = sel[r][k];
            aq += s * Wsq[k * ID + n];
            ak += s * Wsk[k * ID + n];
            av += s * Wsv[k * ID + n];
        }
        sq[r][n] = aq; sk[r][n] = ak; sv[r][n] = av;
    }
    __syncthreads();

    if (t < TOPK * TOPK) {
        const int r = t >> 3, c = t & 7;
        float a = 0.f;
        for (int k = 0; k < 128; k++) a += sq[r][k] * sk[c][k];
        sp[r][c] = a * 0.08838834764831845f;
    }
    __syncthreads();

    if (t < TOPK) {
        float m = -INFINITY;
        for (int c = 0; c < 8; c++) m = fmaxf(m, sp[t][c]);
        float e[8]; float sum = 0.f;
        for (int c = 0; c < 8; c++) { e[c] = expf(sp[t][c] - m); sum += e[c]; }
        for (int c = 0; c < 8; c++) sp[t][c] = e[c] / sum;
    }
    __syncthreads();

    if (t < ID) {
        float acc = 0.f;
        for (int r = 0; r < 8; r++) {
            float so = 0.f;
            for (int c = 0; c < 8; c++) so += sp[r][c] * sv[c][t];
            acc += so;
        }
        ms[t] = acc * 0.125f;
    }
    __syncthreads();

    if (t < ID) {
        float acc = 0.f;
        for (int k = 0; k < 128; k++) acc += ms[k] * Wio[(size_t)k * H_ + t];
        io[((size_t)b * IH + ih) * ID + t] = acc;
    }
}

// ---------------------------------------------------------------------------
// MFMA flash attention v6 (verified R8): one q-tile per block, heavy-first
// dispatch, pipeline staging, defer-max, (256,2) bounds.
// ---------------------------------------------------------------------------
__global__ __launch_bounds__(256, 2) void attn_mfma_k(const bf16* __restrict__ Qp,
                                                      const bf16* __restrict__ Kc,
                                                      const bf16* __restrict__ VbT,
                                                      const float* __restrict__ io,
                                                      bf16* __restrict__ O) {
    __shared__ unsigned short Kt[64 * 200];
    __shared__ unsigned short Vt[128 * 72];
    __shared__ unsigned short Ps[4 * 16 * 72];

    const int lin = blockIdx.x;
    const int qt = 31 - (lin >> 5);            // heavy-first
    const int hb = lin & 31;
    const int h = hb & 15;
    const int b = hb >> 4;
    const int q0 = qt * 64;

    const int t = threadIdx.x;
    const int lane = t & 63;
    const int wq = t >> 6;
    const int col = lane & 15;
    const int quad = lane >> 4;

    const float scale = 0.07216878364870322f;  // 1/sqrt(192)
    const bf16* vplane = VbT + (size_t)(b * NH + h) * 128 * (size_t)S_;

    const int kr = t >> 2;
    const int kc0 = (t & 3) * 48;
    const int vki0 = (t & 7) * 8;
    const int vdv = t >> 3;

    short8 qfrag[6];
    {
        const int q = q0 + wq * 16 + col;
        const short8* qrow = (const short8*)(Qp + ((size_t)(b * S_ + q) * NH + h) * 192);
#pragma unroll
        for (int kc = 0; kc < 6; kc++) qfrag[kc] = qrow[kc * 4 + quad];
    }

    float m_r[4], l_r[4];
#pragma unroll
    for (int r = 0; r < 4; r++) { m_r[r] = -1e30f; l_r[r] = 0.f; }
    f32x4 accO[8];
#pragma unroll
    for (int nt = 0; nt < 8; nt++) accO[nt] = (f32x4){0.f, 0.f, 0.f, 0.f};

    const int nkt = qt + 1;

    short8 kreg[6], vreg[4];
    {
        const short8* ksrc = (const short8*)(Kc + ((size_t)(b * S_ + kr) * NH + h) * 192 + kc0);
#pragma unroll
        for (int c = 0; c < 6; c++) kreg[c] = ksrc[c];
#pragma unroll
        for (int p = 0; p < 4; p++)
            vreg[p] = *(const short8*)(vplane + (size_t)(p * 32 + vdv) * S_ + vki0);
    }

    for (int kt = 0; kt < nkt; kt++) {
        const int kt0 = kt * 64;
        __syncthreads();
        {
            short8* dst = (short8*)&Kt[kr * 200 + kc0];
#pragma unroll
            for (int c = 0; c < 6; c++) dst[c] = kreg[c];
#pragma unroll
            for (int p = 0; p < 4; p++)
                *(short8*)&Vt[(p * 32 + vdv) * 72 + vki0] = vreg[p];
        }
        __syncthreads();

        if (kt + 1 < nkt) {
            const int nk0 = kt0 + 64;
            const short8* ksrc = (const short8*)(Kc + ((size_t)(b * S_ + nk0 + kr) * NH + h) * 192 + kc0);
#pragma unroll
            for (int c = 0; c < 6; c++) kreg[c] = ksrc[c];
#pragma unroll
            for (int p = 0; p < 4; p++)
                vreg[p] = *(const short8*)(vplane + (size_t)(p * 32 + vdv) * S_ + nk0 + vki0);
        }

        f32x4 s[4];
        __builtin_amdgcn_s_setprio(1);
#pragma unroll
        for (int nt = 0; nt < 4; nt++) {
            f32x4 acc = (f32x4){0.f, 0.f, 0.f, 0.f};
#pragma unroll
            for (int kc = 0; kc < 6; kc++) {
                const short8 kf = *(const short8*)&Kt[(nt * 16 + col) * 200 + kc * 32 + quad * 8];
                acc = __builtin_amdgcn_mfma_f32_16x16x32_bf16(qfrag[kc], kf, acc, 0, 0, 0);
            }
            s[nt] = acc;
        }
        __builtin_amdgcn_s_setprio(0);
#pragma unroll
        for (int nt = 0; nt < 4; nt++)
#pragma unroll
            for (int r = 0; r < 4; r++) {
                const int kg = kt0 + nt * 16 + col;
                const int qg = q0 + wq * 16 + quad * 4 + r;
                const float v = s[nt][r] * scale;
                s[nt][r] = (kg > qg) ? -1e30f : v;
            }
        float alpha[4];
#pragma unroll
        for (int r = 0; r < 4; r++) {
            float mt = fmaxf(fmaxf(s[0][r], s[1][r]), fmaxf(s[2][r], s[3][r]));
            mt = fmaxf(mt, __shfl_xor(mt, 1));
            mt = fmaxf(mt, __shfl_xor(mt, 2));
            mt = fmaxf(mt, __shfl_xor(mt, 4));
            mt = fmaxf(mt, __shfl_xor(mt, 8));
            const bool need = (mt > m_r[r] + 8.f);
            const float mn = need ? mt : m_r[r];
            alpha[r] = need ? __expf(m_r[r] - mn) : 1.f;
            m_r[r] = mn;
            float rs = 0.f;
#pragma unroll
            for (int nt = 0; nt < 4; nt++) {
                const float p = __expf(s[nt][r] - mn);
                s[nt][r] = p;
                rs += p;
            }
            rs += __shfl_xor(rs, 1);
            rs += __shfl_xor(rs, 2);
            rs += __shfl_xor(rs, 4);
            rs += __shfl_xor(rs, 8);
            l_r[r] = l_r[r] * alpha[r] + rs;
        }
        {
            unsigned short* pw = &Ps[wq * 1152];
#pragma unroll
            for (int nt = 0; nt < 4; nt++)
#pragma unroll
                for (int r = 0; r < 4; r++) {
                    bf16 hv = f2b(s[nt][r]);
                    pw[(quad * 4 + r) * 72 + nt * 16 + col] = *(unsigned short*)&hv;
                }
        }
        short8 pf[2];
#pragma unroll
        for (int kk = 0; kk < 2; kk++)
            pf[kk] = *(const short8*)&Ps[wq * 1152 + col * 72 + kk * 32 + quad * 8];
        if (!(alpha[0] == 1.f && alpha[1] == 1.f && alpha[2] == 1.f && alpha[3] == 1.f)) {
#pragma unroll
            for (int nt = 0; nt < 8; nt++)
#pragma unroll
                for (int r = 0; r < 4; r++) accO[nt][r] *= alpha[r];
        }
        __builtin_amdgcn_s_setprio(1);
#pragma unroll
        for (int nt = 0; nt < 8; nt++) {
#pragma unroll
            for (int kk = 0; kk < 2; kk++) {
                const short8 vf = *(const short8*)&Vt[(nt * 16 + col) * 72 + kk * 32 + quad * 8];
                accO[nt] = __builtin_amdgcn_mfma_f32_16x16x32_bf16(pf[kk], vf, accO[nt], 0, 0, 0);
            }
        }
        __builtin_amdgcn_s_setprio(0);
    }

    const float* iorow = io + ((size_t)b * IH + (h >> 1)) * ID;
    float rinv[4];
#pragma unroll
    for (int r = 0; r < 4; r++) rinv[r] = 1.f / l_r[r];
#pragma unroll
    for (int nt = 0; nt < 8; nt++) {
        const int dv = nt * 16 + col;
        const float iov = iorow[dv];
#pragma unroll
        for (int r = 0; r < 4; r++) {
            const int q = q0 + wq * 16 + quad * 4 + r;
            O[((size_t)(b * S_ + q) * NH + h) * VD + dv] = f2b(accO[nt][r] * rinv[r] + iov);
        }
    }
}

// ---------------------------------------------------------------------------
// Workspace timeline (within proven ~100.8 MB):
//  S0 = ws+0     (33.5MB): WtM(18.9) -> cqb(12.6)+WqT(9.4 @+12.6M)
//                          -> kvn(16.8) -> attnb(16.8)+WoT(8.4 @+16.8M)
//  S1 = ws+32MB  (25.2MB): cq fp32 -> qp bf16
//  S2 = ws+56MB  (25.2MB): kvc
//  S3 = ws+80MB  (16.8MB): { sel_part(512KB) + sidx(512B @+524288) } -> VbT
//  S4 = ws+96MB  (131KB) : gate -> WkvT
//  S5 = ws+96MB+128KB    : iob
//  xb lives in d_out (dead after gemm_x2; out written last).
// ---------------------------------------------------------------------------
extern "C" void kernel_launch(void* const* d_in, const int* in_sizes, int n_in,
                              void* d_out, int out_size, void* d_ws, size_t ws_size,
                              hipStream_t stream) {
    const float* x      = (const float*)d_in[0];
    const float* W_cq   = (const float*)d_in[1];
    const float* qn_w   = (const float*)d_in[2];
    const float* qn_b   = (const float*)d_in[3];
    const float* W_q    = (const float*)d_in[4];
    const float* W_ckv  = (const float*)d_in[5];
    const float* kvn_w  = (const float*)d_in[6];
    const float* kvn_b  = (const float*)d_in[7];
    const float* W_kv   = (const float*)d_in[8];
    const float* W_o    = (const float*)d_in[9];
    const float* W_ip   = (const float*)d_in[10];
    const float* W_ig   = (const float*)d_in[11];
    const float* W_sq   = (const float*)d_in[12];
    const float* W_sk   = (const float*)d_in[13];
    const float* W_sv   = (const float*)d_in[14];
    const float* W_io   = (const float*)d_in[15];
    float* out = (float*)d_out;

    const int M = B_ * S_;

    char* wsb = (char*)d_ws;
    // S0 tenants
    bf16*  WtM   = (bf16*)wsb;
    bf16*  cqb   = (bf16*)wsb;
    bf16*  WqT   = (bf16*)(wsb + 12582912);
    bf16*  kvn   = (bf16*)wsb;
    bf16*  attnb = (bf16*)wsb;
    bf16*  WoT   = (bf16*)(wsb + 16777216);
    // S1
    float* cq    = (float*)(wsb + 33554432);
    bf16*  qp    = (bf16*)(wsb + 33554432);
    // S2
    bf16*  kvc   = (bf16*)(wsb + 58720256);
    // S3
    float* selp  = (float*)(wsb + 83886080);         // 512 KB sel partials
    int*   sidxb = (int*)(wsb + 83886080 + 524288);  // 512 B
    bf16*  VbT   = (bf16*)(wsb + 83886080);          // after sparse_k
    // S4/S5
    float* gate  = (float*)(wsb + 100663296);
    bf16*  WkvT  = (bf16*)(wsb + 100663296);
    float* iob   = (float*)(wsb + 100794368);
    bf16*  xb    = (bf16*)d_out;

    dim3 blk(256);

    // 1. cast x -> bf16
    cast_bf16_k<<<dim3(2048), blk, 0, stream>>>(x, xb, M * H_ / 4);

    // 2. merged weight transposes: WtM rows [0,1536)=W_cq^T, [1536,4608)=W_ckv^T
    transpose_cast_k<<<dim3(QLR / 32, H_ / 32), blk, 0, stream>>>(W_cq, WtM, H_, QLR);
    transpose_cast_k<<<dim3(3072 / 32, H_ / 32), blk, 0, stream>>>(W_ckv, WtM + (size_t)1536 * H_, H_, 3072);

    // 3. merged GEMM: cq | kvc
    gemm_x2_k<<<dim3(4608 / 128, M / 128), blk, 0, stream>>>(xb, WtM, cq, kvc);

    // 4. LN -> cqb (frees WtM)
    layernorm_cast_k<<<dim3(M), blk, 0, stream>>>(cq, qn_w, qn_b, cqb, QLR);

    // 5-6. qp = cqb @ W_q (plain GEMM; RoPE un-fused), then standalone RoPE
    transpose_cast_k<<<dim3(3072 / 32, QLR / 32), blk, 0, stream>>>(W_q, WqT, QLR, 3072);
    gemm_bt_mfma_k<bf16><<<dim3(3072 / 128, M / 128), blk, 0, stream>>>(cqb, WqT, qp, M, 3072, QLR);
    q_rope_k<<<dim3(2048), blk, 0, stream>>>(qp);

    // 7. gate = x @ W_ig — EXACT fp32
    gate_k<<<dim3(M / 4), blk, 0, stream>>>(x, W_ig, gate);

    // 8-9. sparse selection pipeline at full parallelism
    topk_k<<<dim3(B_ * IH), blk, 0, stream>>>(gate, sidxb);
    sel_k<<<dim3(8, B_ * IH), blk, 0, stream>>>(sidxb, x, W_ip, selp);

    // 10. kv LN (cqb/WqT dead -> kvn in S0)
    kv_ln_k<<<dim3(B_ * S_ * NH / 4), blk, 0, stream>>>(kvc, kvn_w, kvn_b, kvn);

    // 11. sparse finish (consumes selp; frees S3 for VbT)
    sparse_k<<<dim3(B_ * IH), blk, 0, stream>>>(selp, W_sq, W_sk, W_sv, W_io, iob);

    // 12-13. kv matmul (gate dead -> WkvT; selp dead -> VbT)
    transpose_cast_k<<<dim3(256 / 32, 128 / 32), blk, 0, stream>>>(W_kv, WkvT, 128, 256);
    gemm_kv_k<<<dim3(2, (B_ * S_ * NH) / 128), blk, 0, stream>>>(kvn, WkvT, kvc, VbT);

    // 14. attention, heavy-first single-tile grid (kvn dead -> attnb in S0)
    attn_mfma_k<<<dim3(1024), blk, 0, stream>>>(qp, kvc, VbT, iob, attnb);

    // 15-16. out = attnb @ W_o
    transpose_cast_k<<<dim3(H_ / 32, H_ / 32), blk, 0, stream>>>(W_o, WoT, H_, H_);
    gemm_bt_mfma_k<float><<<dim3(H_ / 128, M / 128), blk, 0, stream>>>(attnb, WoT, out, M, H_, H_);
}

// Round 13
// 661.507 us; speedup vs baseline: 1.1886x; 1.0211x over previous
//
#include <hip/hip_runtime.h>
#include <hip/hip_bf16.h>
#include <math.h>

// Problem constants
#define NH    16
#define NOPE  128
#define ROPED 64
#define VD    128
#define QLR   1536
#define IH    8
#define ID    128
#define TOPK  8
#define EPSF  1e-5f
#define B_    2
#define S_    2048
#define H_    2048

using bf16 = __hip_bfloat16;
typedef __attribute__((ext_vector_type(8))) short short8;
typedef __attribute__((ext_vector_type(4))) short short4v;
typedef __attribute__((ext_vector_type(4))) float f32x4;

#define GLOBAL_AS __attribute__((address_space(1)))
#define LDS_AS    __attribute__((address_space(3)))

__device__ __forceinline__ float b2f(bf16 v) { return __bfloat162float(v); }
__device__ __forceinline__ bf16 f2b(float v) { return __float2bfloat16(v); }
__device__ __forceinline__ void stoC(float* p, float v) { *p = v; }
__device__ __forceinline__ void stoC(bf16* p, float v) { *p = __float2bfloat16(v); }

// ---------------------------------------------------------------------------
// Dedicated gate projection (exact fp32, verified R4).
// ---------------------------------------------------------------------------
__global__ __launch_bounds__(256) void gate_k(const float* __restrict__ x,
                                              const float* __restrict__ Wg,
                                              float* __restrict__ gate) {
    const int t = threadIdx.x;
    const int wid = t >> 6, lane = t & 63;
    const int row = blockIdx.x * 4 + wid;
    const float* xp = x + (size_t)row * H_;

    float acc[8] = {};
    for (int k0 = 0; k0 < H_; k0 += 256) {
        const int kb = k0 + lane * 4;
        const f32x4 xv = *(const f32x4*)(xp + kb);
        const f32x4 w0 = *(const f32x4*)(Wg + (size_t)kb * 8);
        const f32x4 w1 = *(const f32x4*)(Wg + (size_t)kb * 8 + 4);
        const f32x4 w2 = *(const f32x4*)(Wg + (size_t)(kb + 1) * 8);
        const f32x4 w3 = *(const f32x4*)(Wg + (size_t)(kb + 1) * 8 + 4);
        const f32x4 w4 = *(const f32x4*)(Wg + (size_t)(kb + 2) * 8);
        const f32x4 w5 = *(const f32x4*)(Wg + (size_t)(kb + 2) * 8 + 4);
        const f32x4 w6 = *(const f32x4*)(Wg + (size_t)(kb + 3) * 8);
        const f32x4 w7 = *(const f32x4*)(Wg + (size_t)(kb + 3) * 8 + 4);
#pragma unroll
        for (int j = 0; j < 4; j++) {
            acc[j]     += xv[0] * w0[j] + xv[1] * w2[j] + xv[2] * w4[j] + xv[3] * w6[j];
            acc[4 + j] += xv[0] * w1[j] + xv[1] * w3[j] + xv[2] * w5[j] + xv[3] * w7[j];
        }
    }
#pragma unroll
    for (int j = 0; j < 8; j++) {
#pragma unroll
        for (int off = 32; off > 0; off >>= 1)
            acc[j] += __shfl_xor(acc[j], off);
    }
    if (lane == 0) {
#pragma unroll
        for (int j = 0; j < 8; j++) gate[(size_t)row * 8 + j] = acc[j];
    }
}

// ---------------------------------------------------------------------------
// bf16 MFMA GEMM v2: m97 fragment layout, BK=64 via split LDS buffers
// (As0/As1/Bs0/Bs1, each the proven [128][32] linear layout -> identical
// bank behavior), HALVING the barrier/vmcnt-drain count vs BK=32.
// LDS 32 KB (5 blocks/CU); XCD chunked swizzle. Requires K % 64 == 0.
// ---------------------------------------------------------------------------
template <typename OT>
__global__ __launch_bounds__(256) void gemm_bt_mfma_k(const bf16* __restrict__ A,
                                                      const bf16* __restrict__ Bt,
                                                      OT* __restrict__ C,
                                                      int M, int N, int K) {
    __shared__ bf16 As0[128 * 32], As1[128 * 32];
    __shared__ bf16 Bs0[128 * 32], Bs1[128 * 32];
    const int t = threadIdx.x;
    const int w = t >> 6;
    const int l = t & 63;
    const int col = l & 15;
    const int quad = l >> 4;
    const int wm = w >> 1, wn = w & 1;

    const int gx = gridDim.x;
    const int nwg = gx * gridDim.y;
    const int lin = blockIdx.y * gx + blockIdx.x;
    const int work = (lin & 7) * (nwg >> 3) + (lin >> 3);
    const int row0 = (work / gx) * 128;
    const int col0 = (work % gx) * 128;

    const int rA = l >> 2;
    const int cA = (l & 3) * 8;
    const bf16* ga0 = A + (size_t)(row0 + w * 16 + rA) * K + cA;
    const bf16* ga1 = A + (size_t)(row0 + (4 + w) * 16 + rA) * K + cA;
    const bf16* gb0 = Bt + (size_t)(col0 + w * 16 + rA) * K + cA;
    const bf16* gb1 = Bt + (size_t)(col0 + (4 + w) * 16 + rA) * K + cA;
    bf16* lA0_0 = &As0[w * 512];
    bf16* lA1_0 = &As0[(4 + w) * 512];
    bf16* lB0_0 = &Bs0[w * 512];
    bf16* lB1_0 = &Bs0[(4 + w) * 512];
    bf16* lA0_1 = &As1[w * 512];
    bf16* lA1_1 = &As1[(4 + w) * 512];
    bf16* lB0_1 = &Bs1[w * 512];
    bf16* lB1_1 = &Bs1[(4 + w) * 512];

    f32x4 acc[4][4];
#pragma unroll
    for (int i = 0; i < 4; i++)
#pragma unroll
        for (int j = 0; j < 4; j++) acc[i][j] = (f32x4){0.f, 0.f, 0.f, 0.f};

    for (int k0 = 0; k0 < K; k0 += 64) {
        __syncthreads();
        __builtin_amdgcn_global_load_lds((const GLOBAL_AS void*)(ga0 + k0),
                                         (LDS_AS void*)lA0_0, 16, 0, 0);
        __builtin_amdgcn_global_load_lds((const GLOBAL_AS void*)(ga1 + k0),
                                         (LDS_AS void*)lA1_0, 16, 0, 0);
        __builtin_amdgcn_global_load_lds((const GLOBAL_AS void*)(gb0 + k0),
                                         (LDS_AS void*)lB0_0, 16, 0, 0);
        __builtin_amdgcn_global_load_lds((const GLOBAL_AS void*)(gb1 + k0),
                                         (LDS_AS void*)lB1_0, 16, 0, 0);
        __builtin_amdgcn_global_load_lds((const GLOBAL_AS void*)(ga0 + k0 + 32),
                                         (LDS_AS void*)lA0_1, 16, 0, 0);
        __builtin_amdgcn_global_load_lds((const GLOBAL_AS void*)(ga1 + k0 + 32),
                                         (LDS_AS void*)lA1_1, 16, 0, 0);
        __builtin_amdgcn_global_load_lds((const GLOBAL_AS void*)(gb0 + k0 + 32),
                                         (LDS_AS void*)lB0_1, 16, 0, 0);
        __builtin_amdgcn_global_load_lds((const GLOBAL_AS void*)(gb1 + k0 + 32),
                                         (LDS_AS void*)lB1_1, 16, 0, 0);
        __syncthreads();

        {
            short8 af[4], bfr[4];
#pragma unroll
            for (int i = 0; i < 4; i++) {
                af[i]  = *(const short8*)&As0[(wm * 64 + i * 16 + col) * 32 + quad * 8];
                bfr[i] = *(const short8*)&Bs0[(wn * 64 + i * 16 + col) * 32 + quad * 8];
            }
#pragma unroll
            for (int i = 0; i < 4; i++)
#pragma unroll
                for (int j = 0; j < 4; j++)
                    acc[i][j] = __builtin_amdgcn_mfma_f32_16x16x32_bf16(af[i], bfr[j], acc[i][j], 0, 0, 0);
        }
        {
            short8 af[4], bfr[4];
#pragma unroll
            for (int i = 0; i < 4; i++) {
                af[i]  = *(const short8*)&As1[(wm * 64 + i * 16 + col) * 32 + quad * 8];
                bfr[i] = *(const short8*)&Bs1[(wn * 64 + i * 16 + col) * 32 + quad * 8];
            }
#pragma unroll
            for (int i = 0; i < 4; i++)
#pragma unroll
                for (int j = 0; j < 4; j++)
                    acc[i][j] = __builtin_amdgcn_mfma_f32_16x16x32_bf16(af[i], bfr[j], acc[i][j], 0, 0, 0);
        }
    }

#pragma unroll
    for (int i = 0; i < 4; i++)
#pragma unroll
        for (int j = 0; j < 4; j++)
#pragma unroll
            for (int r = 0; r < 4; r++) {
                const int gr = row0 + wm * 64 + i * 16 + quad * 4 + r;
                const int gc = col0 + wn * 64 + j * 16 + col;
                stoC(C + (size_t)gr * N + gc, acc[i][j][r]);
            }
}

// ---------------------------------------------------------------------------
// Merged x-projection GEMM, BK=64 split-LDS (same scheme). N = 4608:
// rows [0,1536) = W_cq^T, [1536,4608) = W_ckv^T. Routing block-uniform.
// ---------------------------------------------------------------------------
__global__ __launch_bounds__(256) void gemm_x2_k(const bf16* __restrict__ A,
                                                 const bf16* __restrict__ Bt,
                                                 float* __restrict__ cq,
                                                 bf16* __restrict__ kvc) {
    __shared__ bf16 As0[128 * 32], As1[128 * 32];
    __shared__ bf16 Bs0[128 * 32], Bs1[128 * 32];
    const int K = H_;
    const int t = threadIdx.x;
    const int w = t >> 6;
    const int l = t & 63;
    const int col = l & 15;
    const int quad = l >> 4;
    const int wm = w >> 1, wn = w & 1;

    const int gx = gridDim.x;
    const int nwg = gx * gridDim.y;
    const int lin = blockIdx.y * gx + blockIdx.x;
    const int work = (lin & 7) * (nwg >> 3) + (lin >> 3);
    const int row0 = (work / gx) * 128;
    const int col0 = (work % gx) * 128;

    const int rA = l >> 2;
    const int cA = (l & 3) * 8;
    const bf16* ga0 = A + (size_t)(row0 + w * 16 + rA) * K + cA;
    const bf16* ga1 = A + (size_t)(row0 + (4 + w) * 16 + rA) * K + cA;
    const bf16* gb0 = Bt + (size_t)(col0 + w * 16 + rA) * K + cA;
    const bf16* gb1 = Bt + (size_t)(col0 + (4 + w) * 16 + rA) * K + cA;
    bf16* lA0_0 = &As0[w * 512];
    bf16* lA1_0 = &As0[(4 + w) * 512];
    bf16* lB0_0 = &Bs0[w * 512];
    bf16* lB1_0 = &Bs0[(4 + w) * 512];
    bf16* lA0_1 = &As1[w * 512];
    bf16* lA1_1 = &As1[(4 + w) * 512];
    bf16* lB0_1 = &Bs1[w * 512];
    bf16* lB1_1 = &Bs1[(4 + w) * 512];

    f32x4 acc[4][4];
#pragma unroll
    for (int i = 0; i < 4; i++)
#pragma unroll
        for (int j = 0; j < 4; j++) acc[i][j] = (f32x4){0.f, 0.f, 0.f, 0.f};

    for (int k0 = 0; k0 < K; k0 += 64) {
        __syncthreads();
        __builtin_amdgcn_global_load_lds((const GLOBAL_AS void*)(ga0 + k0),
                                         (LDS_AS void*)lA0_0, 16, 0, 0);
        __builtin_amdgcn_global_load_lds((const GLOBAL_AS void*)(ga1 + k0),
                                         (LDS_AS void*)lA1_0, 16, 0, 0);
        __builtin_amdgcn_global_load_lds((const GLOBAL_AS void*)(gb0 + k0),
                                         (LDS_AS void*)lB0_0, 16, 0, 0);
        __builtin_amdgcn_global_load_lds((const GLOBAL_AS void*)(gb1 + k0),
                                         (LDS_AS void*)lB1_0, 16, 0, 0);
        __builtin_amdgcn_global_load_lds((const GLOBAL_AS void*)(ga0 + k0 + 32),
                                         (LDS_AS void*)lA0_1, 16, 0, 0);
        __builtin_amdgcn_global_load_lds((const GLOBAL_AS void*)(ga1 + k0 + 32),
                                         (LDS_AS void*)lA1_1, 16, 0, 0);
        __builtin_amdgcn_global_load_lds((const GLOBAL_AS void*)(gb0 + k0 + 32),
                                         (LDS_AS void*)lB0_1, 16, 0, 0);
        __builtin_amdgcn_global_load_lds((const GLOBAL_AS void*)(gb1 + k0 + 32),
                                         (LDS_AS void*)lB1_1, 16, 0, 0);
        __syncthreads();

        {
            short8 af[4], bfr[4];
#pragma unroll
            for (int i = 0; i < 4; i++) {
                af[i]  = *(const short8*)&As0[(wm * 64 + i * 16 + col) * 32 + quad * 8];
                bfr[i] = *(const short8*)&Bs0[(wn * 64 + i * 16 + col) * 32 + quad * 8];
            }
#pragma unroll
            for (int i = 0; i < 4; i++)
#pragma unroll
                for (int j = 0; j < 4; j++)
                    acc[i][j] = __builtin_amdgcn_mfma_f32_16x16x32_bf16(af[i], bfr[j], acc[i][j], 0, 0, 0);
        }
        {
            short8 af[4], bfr[4];
#pragma unroll
            for (int i = 0; i < 4; i++) {
                af[i]  = *(const short8*)&As1[(wm * 64 + i * 16 + col) * 32 + quad * 8];
                bfr[i] = *(const short8*)&Bs1[(wn * 64 + i * 16 + col) * 32 + quad * 8];
            }
#pragma unroll
            for (int i = 0; i < 4; i++)
#pragma unroll
                for (int j = 0; j < 4; j++)
                    acc[i][j] = __builtin_amdgcn_mfma_f32_16x16x32_bf16(af[i], bfr[j], acc[i][j], 0, 0, 0);
        }
    }

#pragma unroll
    for (int i = 0; i < 4; i++)
#pragma unroll
        for (int j = 0; j < 4; j++)
#pragma unroll
            for (int r = 0; r < 4; r++) {
                const int gr = row0 + wm * 64 + i * 16 + quad * 4 + r;
                const int gc = col0 + wn * 64 + j * 16 + col;
                const float v = acc[i][j][r];
                if (col0 < 1536) cq[(size_t)gr * QLR + gc] = v;
                else             kvc[(size_t)gr * 3072 + (gc - 1536)] = f2b(v);
            }
}

// ---------------------------------------------------------------------------
// kv matmul on MFMA, BK=64 split-LDS (K=128 -> 2 iterations).
// col-block 0 -> kvc k_nope; col-block 1 -> VbT[bh][dv][s] packed 8B stores.
// ---------------------------------------------------------------------------
__global__ __launch_bounds__(256) void gemm_kv_k(const bf16* __restrict__ A,
                                                 const bf16* __restrict__ Bt,
                                                 bf16* __restrict__ kvc,
                                                 bf16* __restrict__ VbT) {
    __shared__ bf16 As0[128 * 32], As1[128 * 32];
    __shared__ bf16 Bs0[128 * 32], Bs1[128 * 32];
    const int K = 128;
    const int t = threadIdx.x;
    const int w = t >> 6;
    const int l = t & 63;
    const int col = l & 15;
    const int quad = l >> 4;
    const int wm = w >> 1, wn = w & 1;

    const int gx = gridDim.x;
    const int nwg = gx * gridDim.y;
    const int lin = blockIdx.y * gx + blockIdx.x;
    const int work = (lin & 7) * (nwg >> 3) + (lin >> 3);
    const int row0 = (work / gx) * 128;
    const int col0 = (work % gx) * 128;

    const int rA = l >> 2;
    const int cA = (l & 3) * 8;
    const bf16* ga0 = A + (size_t)(row0 + w * 16 + rA) * K + cA;
    const bf16* ga1 = A + (size_t)(row0 + (4 + w) * 16 + rA) * K + cA;
    const bf16* gb0 = Bt + (size_t)(col0 + w * 16 + rA) * K + cA;
    const bf16* gb1 = Bt + (size_t)(col0 + (4 + w) * 16 + rA) * K + cA;
    bf16* lA0_0 = &As0[w * 512];
    bf16* lA1_0 = &As0[(4 + w) * 512];
    bf16* lB0_0 = &Bs0[w * 512];
    bf16* lB1_0 = &Bs0[(4 + w) * 512];
    bf16* lA0_1 = &As1[w * 512];
    bf16* lA1_1 = &As1[(4 + w) * 512];
    bf16* lB0_1 = &Bs1[w * 512];
    bf16* lB1_1 = &Bs1[(4 + w) * 512];

    f32x4 acc[4][4];
#pragma unroll
    for (int i = 0; i < 4; i++)
#pragma unroll
        for (int j = 0; j < 4; j++) acc[i][j] = (f32x4){0.f, 0.f, 0.f, 0.f};

    for (int k0 = 0; k0 < K; k0 += 64) {
        __syncthreads();
        __builtin_amdgcn_global_load_lds((const GLOBAL_AS void*)(ga0 + k0),
                                         (LDS_AS void*)lA0_0, 16, 0, 0);
        __builtin_amdgcn_global_load_lds((const GLOBAL_AS void*)(ga1 + k0),
                                         (LDS_AS void*)lA1_0, 16, 0, 0);
        __builtin_amdgcn_global_load_lds((const GLOBAL_AS void*)(gb0 + k0),
                                         (LDS_AS void*)lB0_0, 16, 0, 0);
        __builtin_amdgcn_global_load_lds((const GLOBAL_AS void*)(gb1 + k0),
                                         (LDS_AS void*)lB1_0, 16, 0, 0);
        __builtin_amdgcn_global_load_lds((const GLOBAL_AS void*)(ga0 + k0 + 32),
                                         (LDS_AS void*)lA0_1, 16, 0, 0);
        __builtin_amdgcn_global_load_lds((const GLOBAL_AS void*)(ga1 + k0 + 32),
                                         (LDS_AS void*)lA1_1, 16, 0, 0);
        __builtin_amdgcn_global_load_lds((const GLOBAL_AS void*)(gb0 + k0 + 32),
                                         (LDS_AS void*)lB0_1, 16, 0, 0);
        __builtin_amdgcn_global_load_lds((const GLOBAL_AS void*)(gb1 + k0 + 32),
                                         (LDS_AS void*)lB1_1, 16, 0, 0);
        __syncthreads();

        {
            short8 af[4], bfr[4];
#pragma unroll
            for (int i = 0; i < 4; i++) {
                af[i]  = *(const short8*)&As0[(wm * 64 + i * 16 + col) * 32 + quad * 8];
                bfr[i] = *(const short8*)&Bs0[(wn * 64 + i * 16 + col) * 32 + quad * 8];
            }
#pragma unroll
            for (int i = 0; i < 4; i++)
#pragma unroll
                for (int j = 0; j < 4; j++)
                    acc[i][j] = __builtin_amdgcn_mfma_f32_16x16x32_bf16(af[i], bfr[j], acc[i][j], 0, 0, 0);
        }
        {
            short8 af[4], bfr[4];
#pragma unroll
            for (int i = 0; i < 4; i++) {
                af[i]  = *(const short8*)&As1[(wm * 64 + i * 16 + col) * 32 + quad * 8];
                bfr[i] = *(const short8*)&Bs1[(wn * 64 + i * 16 + col) * 32 + quad * 8];
            }
#pragma unroll
            for (int i = 0; i < 4; i++)
#pragma unroll
                for (int j = 0; j < 4; j++)
                    acc[i][j] = __builtin_amdgcn_mfma_f32_16x16x32_bf16(af[i], bfr[j], acc[i][j], 0, 0, 0);
        }
    }

    if (col0 == 0) {
#pragma unroll
        for (int i = 0; i < 4; i++)
#pragma unroll
            for (int j = 0; j < 4; j++)
#pragma unroll
                for (int r = 0; r < 4; r++) {
                    const int gr = row0 + wm * 64 + i * 16 + quad * 4 + r;
                    const int gc = wn * 64 + j * 16 + col;
                    kvc[(size_t)gr * 192 + gc] = f2b(acc[i][j][r]);
                }
    } else {
        const int bb = row0 >> 15;
        const int ssb = ((row0 >> 4) & (S_ - 1)) + wm * 4;
#pragma unroll
        for (int j = 0; j < 4; j++) {
            const int dv = wn * 64 + j * 16 + col;
#pragma unroll
            for (int r = 0; r < 4; r++) {
                const int hh = quad * 4 + r;
                short4v pk;
#pragma unroll
                for (int i = 0; i < 4; i++) {
                    bf16 v = f2b(acc[i][j][r]);
                    pk[i] = *(short*)&v;
                }
                *(short4v*)&VbT[((size_t)(bb * NH + hh) * 128 + dv) * S_ + ssb] = pk;
            }
        }
    }
}

// ---------------------------------------------------------------------------
// Wave-per-row LN of kv_nope -> bf16 kvn, plus RoPE of k_pe.
// ---------------------------------------------------------------------------
__global__ __launch_bounds__(256) void kv_ln_k(bf16* __restrict__ kvc,
                                               const float* __restrict__ knw,
                                               const float* __restrict__ knb,
                                               bf16* __restrict__ kvn) {
    const int idx = blockIdx.x * 4 + (threadIdx.x >> 6);   // row 0..65535
    const int lane = threadIdx.x & 63;
    const int s = (idx >> 4) & (S_ - 1);
    const size_t base = (size_t)idx * 192;

    const float v0 = b2f(kvc[base + 64 + lane]);
    const float v1 = b2f(kvc[base + 128 + lane]);
    float xr = 0.f, xi = 0.f;
    if (lane < 32) { xr = b2f(kvc[base + 2 * lane]); xi = b2f(kvc[base + 2 * lane + 1]); }

    float s1 = v0 + v1, s2 = v0 * v0 + v1 * v1;
#pragma unroll
    for (int off = 32; off > 0; off >>= 1) {
        s1 += __shfl_xor(s1, off);
        s2 += __shfl_xor(s2, off);
    }
    const float mu = s1 * (1.f / 128.f);
    const float rinv = rsqrtf(s2 * (1.f / 128.f) - mu * mu + EPSF);
    kvn[(size_t)idx * 128 + lane]      = f2b((v0 - mu) * rinv * knw[lane] + knb[lane]);
    kvn[(size_t)idx * 128 + lane + 64] = f2b((v1 - mu) * rinv * knw[lane + 64] + knb[lane + 64]);

    if (lane < 32) {
        const float freq = exp2f(-0.41524101186092014f * (float)lane); // 10000^(-2l/64)
        const float ang = (float)s * freq;
        float sn, c; sincosf(ang, &sn, &c);
        kvc[base + 128 + 2 * lane]     = f2b(xr * c - xi * sn);
        kvc[base + 128 + 2 * lane + 1] = f2b(xr * sn + xi * c);
    }
}

// ---------------------------------------------------------------------------
// Elementwise fp32 -> bf16 cast.
// ---------------------------------------------------------------------------
__global__ __launch_bounds__(256) void cast_bf16_k(const float* __restrict__ X,
                                                   bf16* __restrict__ Y, int n4) {
    for (int i = blockIdx.x * 256 + threadIdx.x; i < n4; i += gridDim.x * 256) {
        const f32x4 v = ((const f32x4*)X)[i];
        short4v o;
#pragma unroll
        for (int j = 0; j < 4; j++) {
            bf16 b = f2b(v[j]);
            o[j] = *(short*)&b;
        }
        ((short4v*)Y)[i] = o;
    }
}

// ---------------------------------------------------------------------------
// Tiled transpose-cast: W (KxN fp32) -> Wt (NxK bf16).
// ---------------------------------------------------------------------------
__global__ __launch_bounds__(256) void transpose_cast_k(const float* __restrict__ W,
                                                        bf16* __restrict__ Wt,
                                                        int K, int N) {
    __shared__ float tile[32][33];
    const int t = threadIdx.x;
    const int tx = t & 31, ty = t >> 5;
    const int n0 = blockIdx.x * 32;
    const int k0 = blockIdx.y * 32;
#pragma unroll
    for (int i = 0; i < 4; i++)
        tile[ty + 8 * i][tx] = W[(size_t)(k0 + ty + 8 * i) * N + n0 + tx];
    __syncthreads();
#pragma unroll
    for (int i = 0; i < 4; i++)
        Wt[(size_t)(n0 + ty + 8 * i) * K + k0 + tx] = f2b(tile[tx][ty + 8 * i]);
}

// ---------------------------------------------------------------------------
// Row layernorm emitting bf16.
// ---------------------------------------------------------------------------
__global__ __launch_bounds__(256) void layernorm_cast_k(const float* __restrict__ X,
                                                        const float* __restrict__ w,
                                                        const float* __restrict__ b,
                                                        bf16* __restrict__ Y,
                                                        int L) {
    __shared__ float r1[256], r2[256];
    const int row = blockIdx.x;
    const int t = threadIdx.x;
    const float* xp = X + (size_t)row * L;
    bf16* yp = Y + (size_t)row * L;
    float s1 = 0.f, s2 = 0.f;
    for (int j = t; j < L; j += 256) { const float v = xp[j]; s1 += v; s2 += v * v; }
    r1[t] = s1; r2[t] = s2; __syncthreads();
    for (int off = 128; off > 0; off >>= 1) {
        if (t < off) { r1[t] += r1[t + off]; r2[t] += r2[t + off]; }
        __syncthreads();
    }
    const float mu   = r1[0] / (float)L;
    const float var  = r2[0] / (float)L - mu * mu;
    const float rinv = rsqrtf(var + EPSF);
    for (int j = t; j < L; j += 256)
        yp[j] = f2b((xp[j] - mu) * rinv * w[j] + b[j]);
}

// ---------------------------------------------------------------------------
// In-place RoPE on qp (standalone; verified R4-R8/R12).
// ---------------------------------------------------------------------------
__global__ __launch_bounds__(256) void q_rope_k(bf16* __restrict__ qp) {
    const int total = B_ * S_ * NH * 32;
    for (int p = blockIdx.x * 256 + threadIdx.x; p < total; p += gridDim.x * 256) {
        const int j = p & 31;
        const int row = p >> 5;
        const int sr = row >> 4;
        const int s = sr & (S_ - 1);
        const size_t base = (size_t)row * 192 + 128 + 2 * j;
        const float xr = b2f(qp[base]);
        const float xi = b2f(qp[base + 1]);
        const float freq = exp2f(-0.41524101186092014f * (float)j); // 10000^(-2j/64)
        const float ang = (float)s * freq;
        float sn, c; sincosf(ang, &sn, &c);
        qp[base]     = f2b(xr * c - xi * sn);
        qp[base + 1] = f2b(xr * sn + xi * c);
    }
}

// ---------------------------------------------------------------------------
// Top-k selection only (exact fp32). Grid 16 = (b,ih); writes sidx_buf.
// ---------------------------------------------------------------------------
__global__ __launch_bounds__(256) void topk_k(const float* __restrict__ gate,
                                              int* __restrict__ sidx_buf) {
    __shared__ float g[S_];
    __shared__ float rv[256];
    __shared__ int ri[256];
    const int bi = blockIdx.x;
    const int ih = bi % IH;
    const int b = bi / IH;
    const int t = threadIdx.x;

    for (int s = t; s < S_; s += 256) g[s] = gate[(size_t)(b * S_ + s) * IH + ih];
    __syncthreads();

    for (int r = 0; r < TOPK; r++) {
        float bv = -INFINITY; int bx = S_;
        for (int s = t; s < S_; s += 256) {
            const float v = g[s];
            if (v > bv) { bv = v; bx = s; }
        }
        rv[t] = bv; ri[t] = bx; __syncthreads();
        for (int off = 128; off > 0; off >>= 1) {
            if (t < off) {
                const float v2 = rv[t + off]; const int i2 = ri[t + off];
                if (v2 > rv[t] || (v2 == rv[t] && i2 < ri[t])) { rv[t] = v2; ri[t] = i2; }
            }
            __syncthreads();
        }
        if (t == 0) { sidx_buf[bi * TOPK + r] = ri[0]; g[ri[0]] = -INFINITY; }
        __syncthreads();
    }
}

// ---------------------------------------------------------------------------
// sel partials at full parallelism. Grid (8 kc, 16 bi) = 128 blocks.
// ---------------------------------------------------------------------------
__global__ __launch_bounds__(256) void sel_k(const int* __restrict__ sidx_buf,
                                             const float* __restrict__ x,
                                             const float* __restrict__ Wip,
                                             float* __restrict__ sel_part) {
    __shared__ float xs[TOPK][256];   // 8 KB
    __shared__ float sc[8 * 128];     // 4 KB reduce scratch
    const int kc = blockIdx.x;        // 0..7
    const int bi = blockIdx.y;        // 0..15
    const int ih = bi % IH;
    const int b = bi / IH;
    const int t = threadIdx.x;

    for (int i = t; i < TOPK * 256; i += 256) {
        const int r = i >> 8, k = i & 255;
        const int row = sidx_buf[bi * TOPK + r];
        xs[r][k] = x[((size_t)(b * S_ + row)) * H_ + kc * 256 + k];
    }
    __syncthreads();

    const int n4 = (t & 31) * 4;      // col base 0..124
    const int kg = t >> 5;            // k subgroup 0..7 (32 k each)
    f32x4 aa[8];
#pragma unroll
    for (int r = 0; r < 8; r++) aa[r] = (f32x4){0.f, 0.f, 0.f, 0.f};
    for (int k = 0; k < 32; k++) {
        const int kk = kg * 32 + k;
        const f32x4 wv = *(const f32x4*)&Wip[(size_t)(kc * 256 + kk) * (IH * ID) + ih * ID + n4];
#pragma unroll
        for (int r = 0; r < 8; r++) {
            const float xv = xs[r][kk];
#pragma unroll
            for (int e = 0; e < 4; e++) aa[r][e] += xv * wv[e];
        }
    }
#pragma unroll
    for (int r = 0; r < 8; r++) {
        *(f32x4*)&sc[kg * 128 + n4] = aa[r];
        __syncthreads();
        if (t < ID) {
            float a = 0.f;
#pragma unroll
            for (int c = 0; c < 8; c++) a += sc[c * 128 + t];
            sel_part[(((size_t)kc * 16 + bi) * TOPK + r) * ID + t] = a;
        }
        __syncthreads();
    }
}

// ---------------------------------------------------------------------------
// Sparse branch v4: consumes sel_part (sums 8 k-chunks), then the small
// matmuls + softmax + io. Grid 16.
// ---------------------------------------------------------------------------
__global__ __launch_bounds__(256) void sparse_k(const float* __restrict__ sel_part,
                                                const float* __restrict__ Wsq,
                                                const float* __restrict__ Wsk,
                                                const float* __restrict__ Wsv,
                                                const float* __restrict__ Wio,
                                                float* __restrict__ io) {
    __shared__ float sel[TOPK][ID];
    __shared__ float sq[TOPK][ID], sk[TOPK][ID], sv[TOPK][ID];
    __shared__ float sp[TOPK][TOPK];
    __shared__ float ms[ID];
    const int bi = blockIdx.x;
    const int ih = bi % IH;
    const int b = bi / IH;
    const int t = threadIdx.x;

    for (int i = t; i < TOPK * ID; i += 256) {
        const int r = i >> 7, n = i & 127;
        float a = 0.f;
#pragma unroll
        for (int c = 0; c < 8; c++)
            a += sel_part[(((size_t)c * 16 + bi) * TOPK + r) * ID + n];
        sel[r][n] = a;
    }
    __syncthreads();

    for (int i = t; i < TOPK * ID; i += 256) {
        const int r = i >> 7, n = i & 127;
        float aq = 0.f, ak = 0.f, av = 0.f;
        for (int k = 0; k < 128; k++) {
            const float s = sel[r][k];
            aq += s * Wsq[k * ID + n];
            ak += s * Wsk[k * ID + n];
            av += s * Wsv[k * ID + n];
        }
        sq[r][n] = aq; sk[r][n] = ak; sv[r][n] = av;
    }
    __syncthreads();

    if (t < TOPK * TOPK) {
        const int r = t >> 3, c = t & 7;
        float a = 0.f;
        for (int k = 0; k < 128; k++) a += sq[r][k] * sk[c][k];
        sp[r][c] = a * 0.08838834764831845f;
    }
    __syncthreads();

    if (t < TOPK) {
        float m = -INFINITY;
        for (int c = 0; c < 8; c++) m = fmaxf(m, sp[t][c]);
        float e[8]; float sum = 0.f;
        for (int c = 0; c < 8; c++) { e[c] = expf(sp[t][c] - m); sum += e[c]; }
        for (int c = 0; c < 8; c++) sp[t][c] = e[c] / sum;
    }
    __syncthreads();

    if (t < ID) {
        float acc = 0.f;
        for (int r = 0; r < 8; r++) {
            float so = 0.f;
            for (int c = 0; c < 8; c++) so += sp[r][c] * sv[c][t];
            acc += so;
        }
        ms[t] = acc * 0.125f;
    }
    __syncthreads();

    if (t < ID) {
        float acc = 0.f;
        for (int k = 0; k < 128; k++) acc += ms[k] * Wio[(size_t)k * H_ + t];
        io[((size_t)b * IH + ih) * ID + t] = acc;
    }
}

// ---------------------------------------------------------------------------
// MFMA flash attention v6 (verified R8/R12): one q-tile per block,
// heavy-first dispatch, pipeline staging, defer-max, (256,2) bounds.
// ---------------------------------------------------------------------------
__global__ __launch_bounds__(256, 2) void attn_mfma_k(const bf16* __restrict__ Qp,
                                                      const bf16* __restrict__ Kc,
                                                      const bf16* __restrict__ VbT,
                                                      const float* __restrict__ io,
                                                      bf16* __restrict__ O) {
    __shared__ unsigned short Kt[64 * 200];
    __shared__ unsigned short Vt[128 * 72];
    __shared__ unsigned short Ps[4 * 16 * 72];

    const int lin = blockIdx.x;
    const int qt = 31 - (lin >> 5);            // heavy-first
    const int hb = lin & 31;
    const int h = hb & 15;
    const int b = hb >> 4;
    const int q0 = qt * 64;

    const int t = threadIdx.x;
    const int lane = t & 63;
    const int wq = t >> 6;
    const int col = lane & 15;
    const int quad = lane >> 4;

    const float scale = 0.07216878364870322f;  // 1/sqrt(192)
    const bf16* vplane = VbT + (size_t)(b * NH + h) * 128 * (size_t)S_;

    const int kr = t >> 2;
    const int kc0 = (t & 3) * 48;
    const int vki0 = (t & 7) * 8;
    const int vdv = t >> 3;

    short8 qfrag[6];
    {
        const int q = q0 + wq * 16 + col;
        const short8* qrow = (const short8*)(Qp + ((size_t)(b * S_ + q) * NH + h) * 192);
#pragma unroll
        for (int kc = 0; kc < 6; kc++) qfrag[kc] = qrow[kc * 4 + quad];
    }

    float m_r[4], l_r[4];
#pragma unroll
    for (int r = 0; r < 4; r++) { m_r[r] = -1e30f; l_r[r] = 0.f; }
    f32x4 accO[8];
#pragma unroll
    for (int nt = 0; nt < 8; nt++) accO[nt] = (f32x4){0.f, 0.f, 0.f, 0.f};

    const int nkt = qt + 1;

    short8 kreg[6], vreg[4];
    {
        const short8* ksrc = (const short8*)(Kc + ((size_t)(b * S_ + kr) * NH + h) * 192 + kc0);
#pragma unroll
        for (int c = 0; c < 6; c++) kreg[c] = ksrc[c];
#pragma unroll
        for (int p = 0; p < 4; p++)
            vreg[p] = *(const short8*)(vplane + (size_t)(p * 32 + vdv) * S_ + vki0);
    }

    for (int kt = 0; kt < nkt; kt++) {
        const int kt0 = kt * 64;
        __syncthreads();
        {
            short8* dst = (short8*)&Kt[kr * 200 + kc0];
#pragma unroll
            for (int c = 0; c < 6; c++) dst[c] = kreg[c];
#pragma unroll
            for (int p = 0; p < 4; p++)
                *(short8*)&Vt[(p * 32 + vdv) * 72 + vki0] = vreg[p];
        }
        __syncthreads();

        if (kt + 1 < nkt) {
            const int nk0 = kt0 + 64;
            const short8* ksrc = (const short8*)(Kc + ((size_t)(b * S_ + nk0 + kr) * NH + h) * 192 + kc0);
#pragma unroll
            for (int c = 0; c < 6; c++) kreg[c] = ksrc[c];
#pragma unroll
            for (int p = 0; p < 4; p++)
                vreg[p] = *(const short8*)(vplane + (size_t)(p * 32 + vdv) * S_ + nk0 + vki0);
        }

        f32x4 s[4];
        __builtin_amdgcn_s_setprio(1);
#pragma unroll
        for (int nt = 0; nt < 4; nt++) {
            f32x4 acc = (f32x4){0.f, 0.f, 0.f, 0.f};
#pragma unroll
            for (int kc = 0; kc < 6; kc++) {
                const short8 kf = *(const short8*)&Kt[(nt * 16 + col) * 200 + kc * 32 + quad * 8];
                acc = __builtin_amdgcn_mfma_f32_16x16x32_bf16(qfrag[kc], kf, acc, 0, 0, 0);
            }
            s[nt] = acc;
        }
        __builtin_amdgcn_s_setprio(0);
#pragma unroll
        for (int nt = 0; nt < 4; nt++)
#pragma unroll
            for (int r = 0; r < 4; r++) {
                const int kg = kt0 + nt * 16 + col;
                const int qg = q0 + wq * 16 + quad * 4 + r;
                const float v = s[nt][r] * scale;
                s[nt][r] = (kg > qg) ? -1e30f : v;
            }
        float alpha[4];
#pragma unroll
        for (int r = 0; r < 4; r++) {
            float mt = fmaxf(fmaxf(s[0][r], s[1][r]), fmaxf(s[2][r], s[3][r]));
            mt = fmaxf(mt, __shfl_xor(mt, 1));
            mt = fmaxf(mt, __shfl_xor(mt, 2));
            mt = fmaxf(mt, __shfl_xor(mt, 4));
            mt = fmaxf(mt, __shfl_xor(mt, 8));
            const bool need = (mt > m_r[r] + 8.f);
            const float mn = need ? mt : m_r[r];
            alpha[r] = need ? __expf(m_r[r] - mn) : 1.f;
            m_r[r] = mn;
            float rs = 0.f;
#pragma unroll
            for (int nt = 0; nt < 4; nt++) {
                const float p = __expf(s[nt][r] - mn);
                s[nt][r] = p;
                rs += p;
            }
            rs += __shfl_xor(rs, 1);
            rs += __shfl_xor(rs, 2);
            rs += __shfl_xor(rs, 4);
            rs += __shfl_xor(rs, 8);
            l_r[r] = l_r[r] * alpha[r] + rs;
        }
        {
            unsigned short* pw = &Ps[wq * 1152];
#pragma unroll
            for (int nt = 0; nt < 4; nt++)
#pragma unroll
                for (int r = 0; r < 4; r++) {
                    bf16 hv = f2b(s[nt][r]);
                    pw[(quad * 4 + r) * 72 + nt * 16 + col] = *(unsigned short*)&hv;
                }
        }
        short8 pf[2];
#pragma unroll
        for (int kk = 0; kk < 2; kk++)
            pf[kk] = *(const short8*)&Ps[wq * 1152 + col * 72 + kk * 32 + quad * 8];
        if (!(alpha[0] == 1.f && alpha[1] == 1.f && alpha[2] == 1.f && alpha[3] == 1.f)) {
#pragma unroll
            for (int nt = 0; nt < 8; nt++)
#pragma unroll
                for (int r = 0; r < 4; r++) accO[nt][r] *= alpha[r];
        }
        __builtin_amdgcn_s_setprio(1);
#pragma unroll
        for (int nt = 0; nt < 8; nt++) {
#pragma unroll
            for (int kk = 0; kk < 2; kk++) {
                const short8 vf = *(const short8*)&Vt[(nt * 16 + col) * 72 + kk * 32 + quad * 8];
                accO[nt] = __builtin_amdgcn_mfma_f32_16x16x32_bf16(pf[kk], vf, accO[nt], 0, 0, 0);
            }
        }
        __builtin_amdgcn_s_setprio(0);
    }

    const float* iorow = io + ((size_t)b * IH + (h >> 1)) * ID;
    float rinv[4];
#pragma unroll
    for (int r = 0; r < 4; r++) rinv[r] = 1.f / l_r[r];
#pragma unroll
    for (int nt = 0; nt < 8; nt++) {
        const int dv = nt * 16 + col;
        const float iov = iorow[dv];
#pragma unroll
        for (int r = 0; r < 4; r++) {
            const int q = q0 + wq * 16 + quad * 4 + r;
            O[((size_t)(b * S_ + q) * NH + h) * VD + dv] = f2b(accO[nt][r] * rinv[r] + iov);
        }
    }
}

// ---------------------------------------------------------------------------
// Workspace timeline (within proven ~100.8 MB):
//  S0 = ws+0     (33.5MB): WtM(18.9) -> cqb(12.6)+WqT(9.4 @+12.6M)
//                          -> kvn(16.8) -> attnb(16.8)+WoT(8.4 @+16.8M)
//  S1 = ws+32MB  (25.2MB): cq fp32 -> qp bf16
//  S2 = ws+56MB  (25.2MB): kvc
//  S3 = ws+80MB  (16.8MB): { sel_part(512KB) + sidx(512B @+524288) } -> VbT
//  S4 = ws+96MB  (131KB) : gate -> WkvT
//  S5 = ws+96MB+128KB    : iob
//  xb lives in d_out (dead after gemm_x2; out written last).
// ---------------------------------------------------------------------------
extern "C" void kernel_launch(void* const* d_in, const int* in_sizes, int n_in,
                              void* d_out, int out_size, void* d_ws, size_t ws_size,
                              hipStream_t stream) {
    const float* x      = (const float*)d_in[0];
    const float* W_cq   = (const float*)d_in[1];
    const float* qn_w   = (const float*)d_in[2];
    const float* qn_b   = (const float*)d_in[3];
    const float* W_q    = (const float*)d_in[4];
    const float* W_ckv  = (const float*)d_in[5];
    const float* kvn_w  = (const float*)d_in[6];
    const float* kvn_b  = (const float*)d_in[7];
    const float* W_kv   = (const float*)d_in[8];
    const float* W_o    = (const float*)d_in[9];
    const float* W_ip   = (const float*)d_in[10];
    const float* W_ig   = (const float*)d_in[11];
    const float* W_sq   = (const float*)d_in[12];
    const float* W_sk   = (const float*)d_in[13];
    const float* W_sv   = (const float*)d_in[14];
    const float* W_io   = (const float*)d_in[15];
    float* out = (float*)d_out;

    const int M = B_ * S_;

    char* wsb = (char*)d_ws;
    // S0 tenants
    bf16*  WtM   = (bf16*)wsb;
    bf16*  cqb   = (bf16*)wsb;
    bf16*  WqT   = (bf16*)(wsb + 12582912);
    bf16*  kvn   = (bf16*)wsb;
    bf16*  attnb = (bf16*)wsb;
    bf16*  WoT   = (bf16*)(wsb + 16777216);
    // S1
    float* cq    = (float*)(wsb + 33554432);
    bf16*  qp    = (bf16*)(wsb + 33554432);
    // S2
    bf16*  kvc   = (bf16*)(wsb + 58720256);
    // S3
    float* selp  = (float*)(wsb + 83886080);
    int*   sidxb = (int*)(wsb + 83886080 + 524288);
    bf16*  VbT   = (bf16*)(wsb + 83886080);
    // S4/S5
    float* gate  = (float*)(wsb + 100663296);
    bf16*  WkvT  = (bf16*)(wsb + 100663296);
    float* iob   = (float*)(wsb + 100794368);
    bf16*  xb    = (bf16*)d_out;

    dim3 blk(256);

    // 1. cast x -> bf16
    cast_bf16_k<<<dim3(2048), blk, 0, stream>>>(x, xb, M * H_ / 4);

    // 2. merged weight transposes: WtM rows [0,1536)=W_cq^T, [1536,4608)=W_ckv^T
    transpose_cast_k<<<dim3(QLR / 32, H_ / 32), blk, 0, stream>>>(W_cq, WtM, H_, QLR);
    transpose_cast_k<<<dim3(3072 / 32, H_ / 32), blk, 0, stream>>>(W_ckv, WtM + (size_t)1536 * H_, H_, 3072);

    // 3. merged GEMM: cq | kvc (BK=64)
    gemm_x2_k<<<dim3(4608 / 128, M / 128), blk, 0, stream>>>(xb, WtM, cq, kvc);

    // 4. LN -> cqb (frees WtM)
    layernorm_cast_k<<<dim3(M), blk, 0, stream>>>(cq, qn_w, qn_b, cqb, QLR);

    // 5-6. qp = cqb @ W_q (BK=64), then standalone RoPE
    transpose_cast_k<<<dim3(3072 / 32, QLR / 32), blk, 0, stream>>>(W_q, WqT, QLR, 3072);
    gemm_bt_mfma_k<bf16><<<dim3(3072 / 128, M / 128), blk, 0, stream>>>(cqb, WqT, qp, M, 3072, QLR);
    q_rope_k<<<dim3(2048), blk, 0, stream>>>(qp);

    // 7. gate = x @ W_ig — EXACT fp32
    gate_k<<<dim3(M / 4), blk, 0, stream>>>(x, W_ig, gate);

    // 8-9. sparse selection pipeline at full parallelism
    topk_k<<<dim3(B_ * IH), blk, 0, stream>>>(gate, sidxb);
    sel_k<<<dim3(8, B_ * IH), blk, 0, stream>>>(sidxb, x, W_ip, selp);

    // 10. kv LN (cqb/WqT dead -> kvn in S0)
    kv_ln_k<<<dim3(B_ * S_ * NH / 4), blk, 0, stream>>>(kvc, kvn_w, kvn_b, kvn);

    // 11. sparse finish (consumes selp; frees S3 for VbT)
    sparse_k<<<dim3(B_ * IH), blk, 0, stream>>>(selp, W_sq, W_sk, W_sv, W_io, iob);

    // 12-13. kv matmul (gate dead -> WkvT; selp dead -> VbT)
    transpose_cast_k<<<dim3(256 / 32, 128 / 32), blk, 0, stream>>>(W_kv, WkvT, 128, 256);
    gemm_kv_k<<<dim3(2, (B_ * S_ * NH) / 128), blk, 0, stream>>>(kvn, WkvT, kvc, VbT);

    // 14. attention, heavy-first single-tile grid (kvn dead -> attnb in S0)
    attn_mfma_k<<<dim3(1024), blk, 0, stream>>>(qp, kvc, VbT, iob, attnb);

    // 15-16. out = attnb @ W_o (BK=64)
    transpose_cast_k<<<dim3(H_ / 32, H_ / 32), blk, 0, stream>>>(W_o, WoT, H_, H_);
    gemm_bt_mfma_k<float><<<dim3(H_ / 128, M / 128), blk, 0, stream>>>(attnb, WoT, out, M, H_, H_);
}